// Round 9
// baseline (369.752 us; speedup 1.0000x reference)
//
#include <hip/hip_runtime.h>
#include <hip/hip_fp16.h>
#include <math.h>

// ---------------------------------------------------------------------------
// ADCGNN amazon: N=50000, E=1.6M, IN=128, H=64, C=2, K=3
//
// R5: fp16 gather rows (bytes halved; time flat) -> not byte-bound.
// R6: 8-lane retile -> worse (occ). REVERTED.
// R7: wave-private LDS + readlane GEMVs: tail 120us, VALU 74%. [394]
// R10: 8 gather chains -> occ 62%, worse. time ~ 1/waves.
// R11: LDS-broadcast GEMVs: VALU 74->59%, time flat -> L1 weight thrash. [391]
// R12: fp16 dot2 GEMVs (24KB weights fit L1): tail 122->89us. [367 best]
//      Now VALU 48% x 89us = 43us VALU + ~46us constant gather floor.
// R13 (this round): cut gather-accumulate VALU: depth-2 fp16 pairwise tree
//      (v_pk_add_f16) before fp32 accumulate -> 14 VALU/4 edges vs 32.
//      Also hoist tail's independent node-row loads above the gather.
//
// Pipeline:
//   pack_w: Wf1,W3 -> fp16 pair-packed (once)
//   build: bucket_count -> bucket_scan -> bucket_scatter -> csr_build
//   dense1:    h1 = relu(X@W1+b1)
//   dense2res: h, hs=f16(h*dinv), res, th=h.Wattn
//   spmm1:     u1, u1s=f16(u1*dinv), ta      (4-chain gather, pk-tree)
//   tail:      wave/node: gather u2 (pk-tree) -> softmax -> dot2-GEMVs
// ---------------------------------------------------------------------------

#define BSHIFT 7
#define BNODES 128
#define BMAX   512
#define EPT    32
#define CHUNK  (256 * EPT)
#define CAP    8192

typedef _Float16 h2v __attribute__((ext_vector_type(2)));

__device__ __forceinline__ h2v as_h2(unsigned int u) {
    union { unsigned int u; h2v h; } c; c.u = u; return c.h;
}

__device__ __forceinline__ void fma4(float4& acc, float s, const float4 w) {
    acc.x += s * w.x; acc.y += s * w.y; acc.z += s * w.z; acc.w += s * w.w;
}

__device__ __forceinline__ float2 pack_half4(float x, float y, float z, float w) {
    union { __half2 h[2]; float2 f; } u;
    u.h[0] = __floats2half2_rn(x, y);
    u.h[1] = __floats2half2_rn(z, w);
    return u.f;
}

__device__ __forceinline__ void acch4(float4& a, float2 p) {
    union { float2 f; __half2 h[2]; } u; u.f = p;
    float2 lo = __half22float2(u.h[0]);
    float2 hi = __half22float2(u.h[1]);
    a.x += lo.x; a.y += lo.y; a.z += hi.x; a.w += hi.y;
}

// depth-2 fp16 pairwise tree over 4 edges, then fp32 accumulate.
// 6 v_pk_add_f16 + 4 cvt + 4 add = 14 VALU (vs 32 for 4x acch4).
__device__ __forceinline__ void accq(float4& a, float2 pA, float2 pB,
                                     float2 pC, float2 pD) {
    union { float2 f; __half2 h[2]; } A, B, C, D;
    A.f = pA; B.f = pB; C.f = pC; D.f = pD;
    __half2 s0 = __hadd2(__hadd2(A.h[0], B.h[0]), __hadd2(C.h[0], D.h[0]));
    __half2 s1 = __hadd2(__hadd2(A.h[1], B.h[1]), __hadd2(C.h[1], D.h[1]));
    float2 lo = __half22float2(s0), hi = __half22float2(s1);
    a.x += lo.x; a.y += lo.y; a.z += hi.x; a.w += hi.y;
}

// 2-edge variant: 2 pk_add + 4 cvt + 4 add = 10 VALU (vs 16).
__device__ __forceinline__ void accd(float4& a, float2 pA, float2 pB) {
    union { float2 f; __half2 h[2]; } A, B;
    A.f = pA; B.f = pB;
    __half2 s0 = __hadd2(A.h[0], B.h[0]);
    __half2 s1 = __hadd2(A.h[1], B.h[1]);
    float2 lo = __half22float2(s0), hi = __half22float2(s1);
    a.x += lo.x; a.y += lo.y; a.z += hi.x; a.w += hi.y;
}

// ----------------------------- weight pack ---------------------------------

__global__ __launch_bounds__(256) void pack_w_k(const float* __restrict__ Wf1,
                                                const float* __restrict__ W3,
                                                unsigned int* __restrict__ Wf1h,
                                                unsigned int* __restrict__ W3h) {
    int t = blockIdx.x * 256 + threadIdx.x;
    if (t < 64 * 64) {
        int kk = t >> 6, j = t & 63;
        union { __half2 h; unsigned int u; } c;
        c.h = __floats2half2_rn(Wf1[(2 * kk) * 64 + j], Wf1[(2 * kk + 1) * 64 + j]);
        Wf1h[t] = c.u;
    } else if (t < 64 * 64 + 32 * 64) {
        int r = t - 64 * 64;
        int kk = r >> 6, j = r & 63;
        union { __half2 h; unsigned int u; } c;
        c.h = __floats2half2_rn(W3[(2 * kk) * 64 + j], W3[(2 * kk + 1) * 64 + j]);
        W3h[r] = c.u;
    }
}

// ----------------------------- graph build ---------------------------------

__global__ __launch_bounds__(256) void bucket_count_k(const int* __restrict__ dst,
                                                      int* __restrict__ bucketCount,
                                                      int E, int B) {
    __shared__ int cnt[BMAX];
    for (int i = threadIdx.x; i < B; i += 256) cnt[i] = 0;
    __syncthreads();
    int base = blockIdx.x * CHUNK;
    #pragma unroll
    for (int t = 0; t < EPT; t++) {
        int e = base + t * 256 + threadIdx.x;
        if (e < E) atomicAdd(&cnt[dst[e] >> BSHIFT], 1);
    }
    __syncthreads();
    for (int i = threadIdx.x; i < B; i += 256)
        if (cnt[i] > 0) atomicAdd(&bucketCount[i], cnt[i]);
}

__global__ __launch_bounds__(64) void bucket_scan_k(const int* __restrict__ bucketCount,
                                                    int* __restrict__ bucketPtr,
                                                    int* __restrict__ bucketCursor,
                                                    int* __restrict__ rowPtr,
                                                    int B, int N, int E) {
    int lane = threadIdx.x;
    const int PT = (BMAX + 63) / 64;
    int v[PT]; int s = 0;
    #pragma unroll
    for (int t = 0; t < PT; t++) {
        int i = lane * PT + t;
        v[t] = (i < B) ? bucketCount[i] : 0;
        s += v[t];
    }
    int x = s;
    #pragma unroll
    for (int off = 1; off < 64; off <<= 1) {
        int y = __shfl_up(x, off, 64);
        if (lane >= off) x += y;
    }
    int run = x - s;
    #pragma unroll
    for (int t = 0; t < PT; t++) {
        int i = lane * PT + t;
        if (i < B) { bucketPtr[i] = run; bucketCursor[i] = run; }
        run += v[t];
    }
    if (lane == 63) bucketPtr[B] = x;
    if (lane == 0) rowPtr[N] = E;
}

__global__ __launch_bounds__(256) void bucket_scatter_k(const int* __restrict__ src,
                                                        const int* __restrict__ dst,
                                                        int* __restrict__ bucketCursor,
                                                        int* __restrict__ ebuf,
                                                        int E, int B) {
    __shared__ int cnt[BMAX];
    __shared__ int base[BMAX];
    __shared__ int cur[BMAX];
    for (int i = threadIdx.x; i < B; i += 256) { cnt[i] = 0; cur[i] = 0; }
    __syncthreads();
    int cbase = blockIdx.x * CHUNK;
    int d[EPT];
    #pragma unroll
    for (int t = 0; t < EPT; t++) {
        int e = cbase + t * 256 + threadIdx.x;
        d[t] = (e < E) ? dst[e] : -1;
        if (d[t] >= 0) atomicAdd(&cnt[d[t] >> BSHIFT], 1);
    }
    __syncthreads();
    for (int i = threadIdx.x; i < B; i += 256)
        if (cnt[i] > 0) base[i] = atomicAdd(&bucketCursor[i], cnt[i]);
    __syncthreads();
    #pragma unroll
    for (int t = 0; t < EPT; t++) {
        int e = cbase + t * 256 + threadIdx.x;
        if (d[t] >= 0) {
            int b = d[t] >> BSHIFT;
            int c = atomicAdd(&cur[b], 1);
            int pack = (src[e] & 0xFFFF) | ((d[t] & (BNODES - 1)) << 16);
            ebuf[base[b] + c] = pack;
        }
    }
}

__global__ __launch_bounds__(256) void csr_build_k(const int* __restrict__ ebuf,
                                                   const int* __restrict__ bucketPtr,
                                                   int* __restrict__ rowPtr,
                                                   float* __restrict__ dinv,
                                                   int* __restrict__ srcSorted,
                                                   int N) {
    __shared__ int deg[BNODES];
    __shared__ int rp[BNODES + 1];
    __shared__ int cur[BNODES];
    __shared__ int stage[CAP];
    int b = blockIdx.x;
    int nodeBase = b << BSHIFT;
    int nNodes = min(BNODES, N - nodeBase);
    int eBase = bucketPtr[b];
    int eCnt = bucketPtr[b + 1] - eBase;
    for (int i = threadIdx.x; i < BNODES; i += 256) deg[i] = 0;
    __syncthreads();
    for (int i = threadIdx.x; i < eCnt; i += 256)
        atomicAdd(&deg[(ebuf[eBase + i] >> 16) & (BNODES - 1)], 1);
    __syncthreads();
    if (threadIdx.x < 64) {
        int lane = threadIdx.x;
        int d0 = deg[2 * lane], d1 = deg[2 * lane + 1];
        int s = d0 + d1;
        int x = s;
        #pragma unroll
        for (int off = 1; off < 64; off <<= 1) {
            int y = __shfl_up(x, off, 64);
            if (lane >= off) x += y;
        }
        int ex = x - s;
        rp[2 * lane] = ex;
        rp[2 * lane + 1] = ex + d0;
        cur[2 * lane] = ex;
        cur[2 * lane + 1] = ex + d0;
        if (lane == 63) rp[BNODES] = x;
    }
    __syncthreads();
    for (int j = threadIdx.x; j < nNodes; j += 256) {
        rowPtr[nodeBase + j] = eBase + rp[j];
        int dg = deg[j];
        dinv[nodeBase + j] = rsqrtf((float)(dg > 1 ? dg : 1));
    }
    if (eCnt <= CAP) {
        for (int i = threadIdx.x; i < eCnt; i += 256) {
            int p = ebuf[eBase + i];
            int ld = (p >> 16) & (BNODES - 1);
            int pos = atomicAdd(&cur[ld], 1);
            stage[pos] = p & 0xFFFF;
        }
        __syncthreads();
        for (int i = threadIdx.x; i < eCnt; i += 256)
            srcSorted[eBase + i] = stage[i];
    } else {
        for (int i = threadIdx.x; i < eCnt; i += 256) {
            int p = ebuf[eBase + i];
            int ld = (p >> 16) & (BNODES - 1);
            int pos = atomicAdd(&cur[ld], 1);
            srcSorted[eBase + pos] = p & 0xFFFF;
        }
    }
}

// ----------------------------- dense1 --------------------------------------

#define D1_BLK 128
#define D1_PAD 68

__global__ __launch_bounds__(D1_BLK) void dense1_k(const float* __restrict__ Xg,
                                                   const float* __restrict__ W1,
                                                   const float* __restrict__ b1,
                                                   float* __restrict__ h1, int N) {
    __shared__ float lds[D1_BLK * D1_PAD];
    int n0 = blockIdx.x * D1_BLK;
    int n = n0 + threadIdx.x;
    bool act = (n < N);
    const float4* W = (const float4*)W1;
    const float4* B = (const float4*)b1;
    float4 acc[16];
    #pragma unroll
    for (int j = 0; j < 16; j++) acc[j] = B[j];
    if (act) {
        const float4* X = (const float4*)Xg + (size_t)n * 32;
        float4 a = X[0];
        #pragma unroll 1
        for (int kc = 0; kc < 32; kc++) {
            float4 an = a;
            if (kc + 1 < 32) an = X[kc + 1];
            const float4* wrow = W + kc * 64;
            #pragma unroll
            for (int j = 0; j < 16; j++) {
                fma4(acc[j], a.x, wrow[j]);
                fma4(acc[j], a.y, wrow[16 + j]);
                fma4(acc[j], a.z, wrow[32 + j]);
                fma4(acc[j], a.w, wrow[48 + j]);
            }
            a = an;
        }
    }
    float* myrow = &lds[threadIdx.x * D1_PAD];
    #pragma unroll
    for (int j = 0; j < 16; j++) {
        float4 v = acc[j];
        *(float4*)&myrow[4 * j] = make_float4(fmaxf(v.x, 0.f), fmaxf(v.y, 0.f),
                                              fmaxf(v.z, 0.f), fmaxf(v.w, 0.f));
    }
    __syncthreads();
    float4* o4 = (float4*)h1;
    #pragma unroll
    for (int r = 0; r < 16; r++) {
        int idx = r * D1_BLK + threadIdx.x;
        int row = idx >> 4, col = idx & 15;
        int gn = n0 + row;
        if (gn < N) o4[(size_t)gn * 16 + col] = *(float4*)&lds[row * D1_PAD + col * 4];
    }
}

// ----------------------------- dense2res -----------------------------------

#define D2_BLK 128
#define D2_PAD 68

__global__ __launch_bounds__(D2_BLK) void dense2res_k(const float* __restrict__ h1,
                                                      const float* __restrict__ W2,
                                                      const float* __restrict__ b2,
                                                      const float* __restrict__ Wres,
                                                      const float* __restrict__ bres,
                                                      const float* __restrict__ Wattn,
                                                      const float* __restrict__ dinv,
                                                      float* __restrict__ hg,
                                                      float2* __restrict__ hs2,
                                                      float* __restrict__ resg,
                                                      float* __restrict__ thv, int N) {
    __shared__ float lds[D2_BLK * D2_PAD];
    int n0 = blockIdx.x * D2_BLK;
    int n = n0 + threadIdx.x;
    bool act = (n < N);
    const float4* W = (const float4*)W2;
    const float4* B = (const float4*)b2;
    float4 acc[16];
    #pragma unroll
    for (int j = 0; j < 16; j++) acc[j] = B[j];
    if (act) {
        const float4* X = (const float4*)h1 + (size_t)n * 16;
        float4 a = X[0];
        #pragma unroll 1
        for (int kc = 0; kc < 16; kc++) {
            float4 an = a;
            if (kc + 1 < 16) an = X[kc + 1];
            const float4* wrow = W + kc * 64;
            #pragma unroll
            for (int j = 0; j < 16; j++) {
                fma4(acc[j], a.x, wrow[j]);
                fma4(acc[j], a.y, wrow[16 + j]);
                fma4(acc[j], a.z, wrow[32 + j]);
                fma4(acc[j], a.w, wrow[48 + j]);
            }
            a = an;
        }
    }
    const float4* Wa = (const float4*)Wattn;
    float th = 0.f;
    float* myrow = &lds[threadIdx.x * D2_PAD];
    #pragma unroll
    for (int j = 0; j < 16; j++) {
        float4 v = acc[j];
        v.x = fmaxf(v.x, 0.f); v.y = fmaxf(v.y, 0.f);
        v.z = fmaxf(v.z, 0.f); v.w = fmaxf(v.w, 0.f);
        acc[j] = v;
        *(float4*)&myrow[4 * j] = v;
        float4 w = Wa[j];
        th += v.x * w.x + v.y * w.y + v.z * w.z + v.w * w.w;
    }
    if (act) thv[n] = th;
    __syncthreads();
    float4* h4 = (float4*)hg;
    #pragma unroll
    for (int r = 0; r < 16; r++) {
        int idx = r * D2_BLK + threadIdx.x;
        int row = idx >> 4, col = idx & 15;
        int gn = n0 + row;
        if (gn < N) {
            float4 v = *(float4*)&lds[row * D2_PAD + col * 4];
            h4[(size_t)gn * 16 + col] = v;
            float di = dinv[gn];
            hs2[(size_t)gn * 16 + col] =
                pack_half4(v.x * di, v.y * di, v.z * di, v.w * di);
        }
    }
    // res = h @ Wres + bres (h still in regs)
    const float4* WR = (const float4*)Wres;
    const float4* BR = (const float4*)bres;
    float4 acc2[16];
    #pragma unroll
    for (int j = 0; j < 16; j++) acc2[j] = BR[j];
    #pragma unroll 1
    for (int kc = 0; kc < 16; kc++) {
        float4 a2 = acc[kc];
        const float4* wrow = WR + kc * 64;
        #pragma unroll
        for (int j = 0; j < 16; j++) {
            fma4(acc2[j], a2.x, wrow[j]);
            fma4(acc2[j], a2.y, wrow[16 + j]);
            fma4(acc2[j], a2.z, wrow[32 + j]);
            fma4(acc2[j], a2.w, wrow[48 + j]);
        }
    }
    __syncthreads();
    #pragma unroll
    for (int j = 0; j < 16; j++) *(float4*)&myrow[4 * j] = acc2[j];
    __syncthreads();
    float4* r4 = (float4*)resg;
    #pragma unroll
    for (int r = 0; r < 16; r++) {
        int idx = r * D2_BLK + threadIdx.x;
        int row = idx >> 4, col = idx & 15;
        int gn = n0 + row;
        if (gn < N) r4[(size_t)gn * 16 + col] = *(float4*)&lds[row * D2_PAD + col * 4];
    }
}

// ----------------------------- SPMM (spmm1) --------------------------------
// Wave per node (4/block). 16 lanes per f16 row, 4 load chains, depth-2
// fp16 pairwise tree + fp32 accumulate.

__global__ __launch_bounds__(256) void spmm_k(const float2* __restrict__ xs,
                                              const int* __restrict__ srcs,
                                              const int* __restrict__ rowPtr,
                                              const float* __restrict__ dinv,
                                              const float* __restrict__ Wattn,
                                              float4* __restrict__ u,
                                              float2* __restrict__ us,
                                              float* __restrict__ tav, int N) {
    int node = (blockIdx.x * 256 + threadIdx.x) >> 6;
    if (node >= N) return;
    int lane = threadIdx.x & 63;
    int sub = lane >> 4;
    int q = lane & 15;
    int s0 = rowPtr[node], s1 = rowPtr[node + 1];
    float4 a0 = make_float4(0.f, 0.f, 0.f, 0.f);
    int i = s0 + sub;
    for (; i + 12 < s1; i += 16) {
        int sA = srcs[i];
        int sB = srcs[i + 4];
        int sC = srcs[i + 8];
        int sD = srcs[i + 12];
        float2 vA = xs[(size_t)sA * 16 + q];
        float2 vB = xs[(size_t)sB * 16 + q];
        float2 vC = xs[(size_t)sC * 16 + q];
        float2 vD = xs[(size_t)sD * 16 + q];
        accq(a0, vA, vB, vC, vD);
    }
    for (; i + 4 < s1; i += 8) {
        int sA = srcs[i];
        int sB = srcs[i + 4];
        float2 vA = xs[(size_t)sA * 16 + q];
        float2 vB = xs[(size_t)sB * 16 + q];
        accd(a0, vA, vB);
    }
    if (i < s1) {
        float2 vA = xs[(size_t)srcs[i] * 16 + q];
        acch4(a0, vA);
    }
    #pragma unroll
    for (int m = 16; m < 64; m <<= 1) {
        a0.x += __shfl_xor(a0.x, m, 64);
        a0.y += __shfl_xor(a0.y, m, 64);
        a0.z += __shfl_xor(a0.z, m, 64);
        a0.w += __shfl_xor(a0.w, m, 64);
    }
    if (sub == 0) {
        float di = dinv[node];
        float4 r = make_float4(a0.x * di, a0.y * di, a0.z * di, a0.w * di);
        u[(size_t)node * 16 + q] = r;
        us[(size_t)node * 16 + q] =
            pack_half4(r.x * di, r.y * di, r.z * di, r.w * di);
        float4 w = ((const float4*)Wattn)[q];
        float p = r.x * w.x + r.y * w.y + r.z * w.z + r.w * w.w;
        #pragma unroll
        for (int m = 1; m < 16; m <<= 1) p += __shfl_xor(p, m, 64);
        if (lane == 0) tav[node] = p;
    }
}

// ----------------------------- fused spmm2 + tail --------------------------
// Wave per node (4/block), no block barrier. pk-tree gather; node-row loads
// hoisted above the gather so their latency hides under it; dot2 GEMVs.

#define TL_PAD 68
#define BS_HPAD 136

__global__ __launch_bounds__(256) void tail_k(const float2* __restrict__ u1s,
                                              const int* __restrict__ srcs,
                                              const int* __restrict__ rowPtr,
                                              const float* __restrict__ dinv,
                                              const float* __restrict__ hg,
                                              const float* __restrict__ u1g,
                                              const float* __restrict__ resg,
                                              const float* __restrict__ thv,
                                              const float* __restrict__ tav,
                                              const float* __restrict__ Wattn,
                                              const float* __restrict__ battn,
                                              const unsigned int* __restrict__ Wf1h,
                                              const float* __restrict__ bf1,
                                              const float* __restrict__ Wf2,
                                              const float* __restrict__ bf2,
                                              const unsigned int* __restrict__ W3h,
                                              const float* __restrict__ b3,
                                              const float* __restrict__ W4,
                                              const float* __restrict__ b4,
                                              float2* __restrict__ out, int N) {
    __shared__ float lds[4 * TL_PAD];
    __shared__ _Float16 bsl[4 * BS_HPAD];
    int w = threadIdx.x >> 6;
    int lane = threadIdx.x & 63;
    int node = blockIdx.x * 4 + w;
    if (node >= N) return;
    int sub = lane >> 4, q = lane & 15;
    // hoisted independent loads: in flight during the gather below
    float hj = hg[(size_t)node * 64 + lane];
    float u1j = u1g[(size_t)node * 64 + lane];
    float resj = resg[(size_t)node * 64 + lane];
    float th = thv[node], ta = tav[node], ba = battn[0];
    float waj = Wattn[lane];
    float dinv_n = dinv[node];
    {
        int s0 = rowPtr[node], s1 = rowPtr[node + 1];
        float4 a0 = make_float4(0.f, 0.f, 0.f, 0.f);
        int i = s0 + sub;
        for (; i + 12 < s1; i += 16) {
            int sA = srcs[i];
            int sB = srcs[i + 4];
            int sC = srcs[i + 8];
            int sD = srcs[i + 12];
            float2 vA = u1s[(size_t)sA * 16 + q];
            float2 vB = u1s[(size_t)sB * 16 + q];
            float2 vC = u1s[(size_t)sC * 16 + q];
            float2 vD = u1s[(size_t)sD * 16 + q];
            accq(a0, vA, vB, vC, vD);
        }
        for (; i + 4 < s1; i += 8) {
            int sA = srcs[i];
            int sB = srcs[i + 4];
            float2 vA = u1s[(size_t)sA * 16 + q];
            float2 vB = u1s[(size_t)sB * 16 + q];
            accd(a0, vA, vB);
        }
        if (i < s1) {
            float2 vA = u1s[(size_t)srcs[i] * 16 + q];
            acch4(a0, vA);
        }
        #pragma unroll
        for (int m = 16; m < 64; m <<= 1) {
            a0.x += __shfl_xor(a0.x, m, 64);
            a0.y += __shfl_xor(a0.y, m, 64);
            a0.z += __shfl_xor(a0.z, m, 64);
            a0.w += __shfl_xor(a0.w, m, 64);
        }
        if (sub == 0) {
            *(float4*)&lds[w * TL_PAD + q * 4] =
                make_float4(a0.x * dinv_n, a0.y * dinv_n,
                            a0.z * dinv_n, a0.w * dinv_n);
        }
    }
    // wave-private LDS: same wave wrote it; DS ops in-order per wave.
    float u2j = lds[w * TL_PAD + lane];                  // feature j = lane
    // tb = u2 . Wattn
    float tb = u2j * waj;
    #pragma unroll
    for (int m = 1; m < 64; m <<= 1) tb += __shfl_xor(tb, m, 64);
    float s0 = 0.75f * th + 1.5f * ta + 0.75f * tb + ba;
    float s1 = 1.5f * th - 1.5f * tb + ba;
    float s2 = 0.75f * th - 1.5f * ta + 0.75f * tb + ba;
    float mx = fmaxf(s0, fmaxf(s1, s2));
    float e0 = expf(s0 - mx), e1 = expf(s1 - mx), e2 = expf(s2 - mx);
    float inv = 1.f / (e0 + e1 + e2);
    float w0 = e0 * inv, w1 = e1 * inv, w2 = e2 * inv;
    float ca = 0.75f * w0 + 1.5f * w1 + 0.75f * w2;
    float cb = 1.5f * (w0 - w2);
    float cc = 0.75f * w0 - 1.5f * w1 + 0.75f * w2;
    float afj = ca * hj + cb * u1j + cc * u2j;
    // stage af | h as fp16 into the wave's broadcast slice
    _Float16* bsh = &bsl[w * BS_HPAD];
    bsh[lane] = (_Float16)afj;
    bsh[64 + lane] = (_Float16)hj;
    // t = relu([af|h] @ Wf1 + bf1): dot2 GEMV over 64 packed pairs
    float t0 = bf1[lane], t1 = 0.f, t2 = 0.f, t3 = 0.f;
    #pragma unroll 1
    for (int kk = 0; kk < 64; kk += 4) {
        uint4 br = *(const uint4*)&bsh[2 * kk];   // pairs kk..kk+3 (16B)
        unsigned int w0_ = Wf1h[(kk + 0) * 64 + lane];
        unsigned int w1_ = Wf1h[(kk + 1) * 64 + lane];
        unsigned int w2_ = Wf1h[(kk + 2) * 64 + lane];
        unsigned int w3_ = Wf1h[(kk + 3) * 64 + lane];
        t0 = __builtin_amdgcn_fdot2(as_h2(br.x), as_h2(w0_), t0, false);
        t1 = __builtin_amdgcn_fdot2(as_h2(br.y), as_h2(w1_), t1, false);
        t2 = __builtin_amdgcn_fdot2(as_h2(br.z), as_h2(w2_), t2, false);
        t3 = __builtin_amdgcn_fdot2(as_h2(br.w), as_h2(w3_), t3, false);
    }
    float t = fmaxf((t0 + t1) + (t2 + t3), 0.f);
    float fwacc = t * Wf2[lane];
    #pragma unroll
    for (int m = 1; m < 64; m <<= 1) fwacc += __shfl_xor(fwacc, m, 64);
    float fw = 1.f / (1.f + expf(-(fwacc + bf2[0])));
    // fused = 0.1*fw*af + (1-fw)*h + 0.8*res   (mean_fused == h exactly)
    float fj = 0.1f * fw * afj + (1.f - fw) * hj + 0.8f * resj;
    bsh[lane] = (_Float16)fj;   // overwrite af slot (in-order DS)
    float g0 = b3[lane], g1 = 0.f, g2 = 0.f, g3 = 0.f;
    #pragma unroll 1
    for (int kk = 0; kk < 32; kk += 4) {
        uint4 br = *(const uint4*)&bsh[2 * kk];   // pairs kk..kk+3
        unsigned int w0_ = W3h[(kk + 0) * 64 + lane];
        unsigned int w1_ = W3h[(kk + 1) * 64 + lane];
        unsigned int w2_ = W3h[(kk + 2) * 64 + lane];
        unsigned int w3_ = W3h[(kk + 3) * 64 + lane];
        g0 = __builtin_amdgcn_fdot2(as_h2(br.x), as_h2(w0_), g0, false);
        g1 = __builtin_amdgcn_fdot2(as_h2(br.y), as_h2(w1_), g1, false);
        g2 = __builtin_amdgcn_fdot2(as_h2(br.z), as_h2(w2_), g2, false);
        g3 = __builtin_amdgcn_fdot2(as_h2(br.w), as_h2(w3_), g3, false);
    }
    float g = fmaxf((g0 + g1) + (g2 + g3), 0.f);
    float2 w4 = ((const float2*)W4)[lane];
    float l0 = g * w4.x, l1 = g * w4.y;
    #pragma unroll
    for (int m = 1; m < 64; m <<= 1) {
        l0 += __shfl_xor(l0, m, 64);
        l1 += __shfl_xor(l1, m, 64);
    }
    if (lane == 0) out[node] = make_float2(l0 + b4[0], l1 + b4[1]);
}

// ----------------------------- launch --------------------------------------

extern "C" void kernel_launch(void* const* d_in, const int* in_sizes, int n_in,
                              void* d_out, int out_size, void* d_ws, size_t ws_size,
                              hipStream_t stream) {
    const float* in_feat = (const float*)d_in[0];
    const int*   src     = (const int*)d_in[1];
    const int*   dst     = (const int*)d_in[2];
    const float* W1   = (const float*)d_in[3];
    const float* b1   = (const float*)d_in[4];
    const float* W2   = (const float*)d_in[5];
    const float* b2   = (const float*)d_in[6];
    const float* Wres = (const float*)d_in[7];
    const float* bres = (const float*)d_in[8];
    const float* Wattn = (const float*)d_in[9];
    const float* battn = (const float*)d_in[10];
    const float* Wf1  = (const float*)d_in[11];
    const float* bf1  = (const float*)d_in[12];
    const float* Wf2  = (const float*)d_in[13];
    const float* bf2  = (const float*)d_in[14];
    const float* W3   = (const float*)d_in[15];
    const float* b3   = (const float*)d_in[16];
    const float* W4   = (const float*)d_in[17];
    const float* b4   = (const float*)d_in[18];

    const int N = in_sizes[0] / 128;
    const int E = in_sizes[1];
    const int B = (N + BNODES - 1) >> BSHIFT;

    char* p = (char*)d_ws;
    auto take = [&](size_t bytes) -> char* {
        char* r = p;
        p += (bytes + 255) & ~(size_t)255;
        return r;
    };
    int*   bucketCount  = (int*)take((size_t)(B + 1) * 4);
    int*   bucketPtr    = (int*)take((size_t)(B + 1) * 4);
    int*   bucketCursor = (int*)take((size_t)(B + 1) * 4);
    int*   rowPtr       = (int*)take((size_t)(N + 1) * 4);
    float* dinv         = (float*)take((size_t)N * 4);
    int*   srcSorted    = (int*)take((size_t)E * 4);
    float* thv          = (float*)take((size_t)N * 4);
    float* tav          = (float*)take((size_t)N * 4);
    unsigned int* Wf1h  = (unsigned int*)take((size_t)64 * 64 * 4);
    unsigned int* W3h   = (unsigned int*)take((size_t)32 * 64 * 4);
    float* h1  = (float*)take((size_t)N * 256);
    float* h   = (float*)take((size_t)N * 256);
    float* hs  = (float*)take((size_t)N * 128);   // f16 packed, 64 halves/row
    float* res = (float*)take((size_t)N * 256);
    float* u1  = (float*)take((size_t)N * 256);
    float* u1s = (float*)take((size_t)N * 128);   // f16 packed
    int*   ebuf = (int*)h1;   // dead before dense1 writes h1 (stream order)

    int eb = (E + CHUNK - 1) / CHUNK;
    int d1b = (N + D1_BLK - 1) / D1_BLK;
    int d2b = (N + D2_BLK - 1) / D2_BLK;
    int spb = (N * 64 + 255) / 256;
    int tlb = (N + 3) / 4;

    pack_w_k<<<24, 256, 0, stream>>>(Wf1, W3, Wf1h, W3h);

    hipMemsetAsync(bucketCount, 0, (size_t)B * 4, stream);
    bucket_count_k<<<eb, 256, 0, stream>>>(dst, bucketCount, E, B);
    bucket_scan_k<<<1, 64, 0, stream>>>(bucketCount, bucketPtr, bucketCursor,
                                        rowPtr, B, N, E);
    bucket_scatter_k<<<eb, 256, 0, stream>>>(src, dst, bucketCursor, ebuf, E, B);
    csr_build_k<<<B, 256, 0, stream>>>(ebuf, bucketPtr, rowPtr, dinv, srcSorted, N);

    dense1_k<<<d1b, D1_BLK, 0, stream>>>(in_feat, W1, b1, h1, N);
    dense2res_k<<<d2b, D2_BLK, 0, stream>>>(h1, W2, b2, Wres, bres, Wattn, dinv,
                                            h, (float2*)hs, res, thv, N);

    spmm_k<<<spb, 256, 0, stream>>>((const float2*)hs, srcSorted, rowPtr, dinv,
                                    Wattn, (float4*)u1, (float2*)u1s, tav, N);

    tail_k<<<tlb, 256, 0, stream>>>((const float2*)u1s, srcSorted, rowPtr, dinv,
                                    h, u1, res, thv, tav, Wattn, battn,
                                    Wf1h, bf1, Wf2, bf2, W3h, b3, W4, b4,
                                    (float2*)d_out, N);
}

// Round 10
// 362.298 us; speedup vs baseline: 1.0206x; 1.0206x over previous
//
#include <hip/hip_runtime.h>
#include <hip/hip_fp16.h>
#include <math.h>

// ---------------------------------------------------------------------------
// ADCGNN amazon: N=50000, E=1.6M, IN=128, H=64, C=2, K=3
//
// R5: fp16 gather rows (bytes halved; time flat) -> not byte-bound.
// R6: 8-lane retile -> worse (occ). REVERTED.
// R7: wave-private LDS + readlane GEMVs: tail 120us, VALU 74%. [394]
// R10: 8 gather chains -> occ 62%, worse. time ~ 1/waves (when VALU-bound).
// R11: LDS-broadcast GEMVs: VALU 74->59%, time flat -> L1 weight thrash. [391]
// R12: fp16 dot2 GEMVs (24KB weights fit L1): tail 122->89us. [367 best]
// R13: pk-tree gather accumulate: VALU 48->43%, time FLAT -> VALU now below
//      the ~46us non-VALU floor. Floor = gather memory latency exposure.
// R14 (this round): src-index rotation (1-deep software pipeline). Today
//      each 16-edge iter exposes TWO serial latencies (srcs wait, then
//      gather wait; vmcnt retires in-order). Rotating srcs one iter ahead
//      makes gather addrs register-ready at iter start -> one latency/iter.
//
// Pipeline:
//   pack_w: Wf1,W3 -> fp16 pair-packed (once)
//   build: bucket_count -> bucket_scan -> bucket_scatter -> csr_build
//   dense1:    h1 = relu(X@W1+b1)
//   dense2res: h, hs=f16(h*dinv), res, th=h.Wattn
//   spmm1:     u1, u1s=f16(u1*dinv), ta      (rotated-index gather)
//   tail:      wave/node: gather u2 (rotated) -> softmax -> dot2-GEMVs
// ---------------------------------------------------------------------------

#define BSHIFT 7
#define BNODES 128
#define BMAX   512
#define EPT    32
#define CHUNK  (256 * EPT)
#define CAP    8192

typedef _Float16 h2v __attribute__((ext_vector_type(2)));

__device__ __forceinline__ h2v as_h2(unsigned int u) {
    union { unsigned int u; h2v h; } c; c.u = u; return c.h;
}

__device__ __forceinline__ void fma4(float4& acc, float s, const float4 w) {
    acc.x += s * w.x; acc.y += s * w.y; acc.z += s * w.z; acc.w += s * w.w;
}

__device__ __forceinline__ float2 pack_half4(float x, float y, float z, float w) {
    union { __half2 h[2]; float2 f; } u;
    u.h[0] = __floats2half2_rn(x, y);
    u.h[1] = __floats2half2_rn(z, w);
    return u.f;
}

__device__ __forceinline__ void acch4(float4& a, float2 p) {
    union { float2 f; __half2 h[2]; } u; u.f = p;
    float2 lo = __half22float2(u.h[0]);
    float2 hi = __half22float2(u.h[1]);
    a.x += lo.x; a.y += lo.y; a.z += hi.x; a.w += hi.y;
}

// depth-2 fp16 pairwise tree over 4 edges, then fp32 accumulate.
__device__ __forceinline__ void accq(float4& a, float2 pA, float2 pB,
                                     float2 pC, float2 pD) {
    union { float2 f; __half2 h[2]; } A, B, C, D;
    A.f = pA; B.f = pB; C.f = pC; D.f = pD;
    __half2 s0 = __hadd2(__hadd2(A.h[0], B.h[0]), __hadd2(C.h[0], D.h[0]));
    __half2 s1 = __hadd2(__hadd2(A.h[1], B.h[1]), __hadd2(C.h[1], D.h[1]));
    float2 lo = __half22float2(s0), hi = __half22float2(s1);
    a.x += lo.x; a.y += lo.y; a.z += hi.x; a.w += hi.y;
}

// 2-edge variant.
__device__ __forceinline__ void accd(float4& a, float2 pA, float2 pB) {
    union { float2 f; __half2 h[2]; } A, B;
    A.f = pA; B.f = pB;
    __half2 s0 = __hadd2(A.h[0], B.h[0]);
    __half2 s1 = __hadd2(A.h[1], B.h[1]);
    float2 lo = __half22float2(s0), hi = __half22float2(s1);
    a.x += lo.x; a.y += lo.y; a.z += hi.x; a.w += hi.y;
}

// ----------------------------- weight pack ---------------------------------

__global__ __launch_bounds__(256) void pack_w_k(const float* __restrict__ Wf1,
                                                const float* __restrict__ W3,
                                                unsigned int* __restrict__ Wf1h,
                                                unsigned int* __restrict__ W3h) {
    int t = blockIdx.x * 256 + threadIdx.x;
    if (t < 64 * 64) {
        int kk = t >> 6, j = t & 63;
        union { __half2 h; unsigned int u; } c;
        c.h = __floats2half2_rn(Wf1[(2 * kk) * 64 + j], Wf1[(2 * kk + 1) * 64 + j]);
        Wf1h[t] = c.u;
    } else if (t < 64 * 64 + 32 * 64) {
        int r = t - 64 * 64;
        int kk = r >> 6, j = r & 63;
        union { __half2 h; unsigned int u; } c;
        c.h = __floats2half2_rn(W3[(2 * kk) * 64 + j], W3[(2 * kk + 1) * 64 + j]);
        W3h[r] = c.u;
    }
}

// ----------------------------- graph build ---------------------------------

__global__ __launch_bounds__(256) void bucket_count_k(const int* __restrict__ dst,
                                                      int* __restrict__ bucketCount,
                                                      int E, int B) {
    __shared__ int cnt[BMAX];
    for (int i = threadIdx.x; i < B; i += 256) cnt[i] = 0;
    __syncthreads();
    int base = blockIdx.x * CHUNK;
    #pragma unroll
    for (int t = 0; t < EPT; t++) {
        int e = base + t * 256 + threadIdx.x;
        if (e < E) atomicAdd(&cnt[dst[e] >> BSHIFT], 1);
    }
    __syncthreads();
    for (int i = threadIdx.x; i < B; i += 256)
        if (cnt[i] > 0) atomicAdd(&bucketCount[i], cnt[i]);
}

__global__ __launch_bounds__(64) void bucket_scan_k(const int* __restrict__ bucketCount,
                                                    int* __restrict__ bucketPtr,
                                                    int* __restrict__ bucketCursor,
                                                    int* __restrict__ rowPtr,
                                                    int B, int N, int E) {
    int lane = threadIdx.x;
    const int PT = (BMAX + 63) / 64;
    int v[PT]; int s = 0;
    #pragma unroll
    for (int t = 0; t < PT; t++) {
        int i = lane * PT + t;
        v[t] = (i < B) ? bucketCount[i] : 0;
        s += v[t];
    }
    int x = s;
    #pragma unroll
    for (int off = 1; off < 64; off <<= 1) {
        int y = __shfl_up(x, off, 64);
        if (lane >= off) x += y;
    }
    int run = x - s;
    #pragma unroll
    for (int t = 0; t < PT; t++) {
        int i = lane * PT + t;
        if (i < B) { bucketPtr[i] = run; bucketCursor[i] = run; }
        run += v[t];
    }
    if (lane == 63) bucketPtr[B] = x;
    if (lane == 0) rowPtr[N] = E;
}

__global__ __launch_bounds__(256) void bucket_scatter_k(const int* __restrict__ src,
                                                        const int* __restrict__ dst,
                                                        int* __restrict__ bucketCursor,
                                                        int* __restrict__ ebuf,
                                                        int E, int B) {
    __shared__ int cnt[BMAX];
    __shared__ int base[BMAX];
    __shared__ int cur[BMAX];
    for (int i = threadIdx.x; i < B; i += 256) { cnt[i] = 0; cur[i] = 0; }
    __syncthreads();
    int cbase = blockIdx.x * CHUNK;
    int d[EPT];
    #pragma unroll
    for (int t = 0; t < EPT; t++) {
        int e = cbase + t * 256 + threadIdx.x;
        d[t] = (e < E) ? dst[e] : -1;
        if (d[t] >= 0) atomicAdd(&cnt[d[t] >> BSHIFT], 1);
    }
    __syncthreads();
    for (int i = threadIdx.x; i < B; i += 256)
        if (cnt[i] > 0) base[i] = atomicAdd(&bucketCursor[i], cnt[i]);
    __syncthreads();
    #pragma unroll
    for (int t = 0; t < EPT; t++) {
        int e = cbase + t * 256 + threadIdx.x;
        if (d[t] >= 0) {
            int b = d[t] >> BSHIFT;
            int c = atomicAdd(&cur[b], 1);
            int pack = (src[e] & 0xFFFF) | ((d[t] & (BNODES - 1)) << 16);
            ebuf[base[b] + c] = pack;
        }
    }
}

__global__ __launch_bounds__(256) void csr_build_k(const int* __restrict__ ebuf,
                                                   const int* __restrict__ bucketPtr,
                                                   int* __restrict__ rowPtr,
                                                   float* __restrict__ dinv,
                                                   int* __restrict__ srcSorted,
                                                   int N) {
    __shared__ int deg[BNODES];
    __shared__ int rp[BNODES + 1];
    __shared__ int cur[BNODES];
    __shared__ int stage[CAP];
    int b = blockIdx.x;
    int nodeBase = b << BSHIFT;
    int nNodes = min(BNODES, N - nodeBase);
    int eBase = bucketPtr[b];
    int eCnt = bucketPtr[b + 1] - eBase;
    for (int i = threadIdx.x; i < BNODES; i += 256) deg[i] = 0;
    __syncthreads();
    for (int i = threadIdx.x; i < eCnt; i += 256)
        atomicAdd(&deg[(ebuf[eBase + i] >> 16) & (BNODES - 1)], 1);
    __syncthreads();
    if (threadIdx.x < 64) {
        int lane = threadIdx.x;
        int d0 = deg[2 * lane], d1 = deg[2 * lane + 1];
        int s = d0 + d1;
        int x = s;
        #pragma unroll
        for (int off = 1; off < 64; off <<= 1) {
            int y = __shfl_up(x, off, 64);
            if (lane >= off) x += y;
        }
        int ex = x - s;
        rp[2 * lane] = ex;
        rp[2 * lane + 1] = ex + d0;
        cur[2 * lane] = ex;
        cur[2 * lane + 1] = ex + d0;
        if (lane == 63) rp[BNODES] = x;
    }
    __syncthreads();
    for (int j = threadIdx.x; j < nNodes; j += 256) {
        rowPtr[nodeBase + j] = eBase + rp[j];
        int dg = deg[j];
        dinv[nodeBase + j] = rsqrtf((float)(dg > 1 ? dg : 1));
    }
    if (eCnt <= CAP) {
        for (int i = threadIdx.x; i < eCnt; i += 256) {
            int p = ebuf[eBase + i];
            int ld = (p >> 16) & (BNODES - 1);
            int pos = atomicAdd(&cur[ld], 1);
            stage[pos] = p & 0xFFFF;
        }
        __syncthreads();
        for (int i = threadIdx.x; i < eCnt; i += 256)
            srcSorted[eBase + i] = stage[i];
    } else {
        for (int i = threadIdx.x; i < eCnt; i += 256) {
            int p = ebuf[eBase + i];
            int ld = (p >> 16) & (BNODES - 1);
            int pos = atomicAdd(&cur[ld], 1);
            srcSorted[eBase + pos] = p & 0xFFFF;
        }
    }
}

// ----------------------------- dense1 --------------------------------------

#define D1_BLK 128
#define D1_PAD 68

__global__ __launch_bounds__(D1_BLK) void dense1_k(const float* __restrict__ Xg,
                                                   const float* __restrict__ W1,
                                                   const float* __restrict__ b1,
                                                   float* __restrict__ h1, int N) {
    __shared__ float lds[D1_BLK * D1_PAD];
    int n0 = blockIdx.x * D1_BLK;
    int n = n0 + threadIdx.x;
    bool act = (n < N);
    const float4* W = (const float4*)W1;
    const float4* B = (const float4*)b1;
    float4 acc[16];
    #pragma unroll
    for (int j = 0; j < 16; j++) acc[j] = B[j];
    if (act) {
        const float4* X = (const float4*)Xg + (size_t)n * 32;
        float4 a = X[0];
        #pragma unroll 1
        for (int kc = 0; kc < 32; kc++) {
            float4 an = a;
            if (kc + 1 < 32) an = X[kc + 1];
            const float4* wrow = W + kc * 64;
            #pragma unroll
            for (int j = 0; j < 16; j++) {
                fma4(acc[j], a.x, wrow[j]);
                fma4(acc[j], a.y, wrow[16 + j]);
                fma4(acc[j], a.z, wrow[32 + j]);
                fma4(acc[j], a.w, wrow[48 + j]);
            }
            a = an;
        }
    }
    float* myrow = &lds[threadIdx.x * D1_PAD];
    #pragma unroll
    for (int j = 0; j < 16; j++) {
        float4 v = acc[j];
        *(float4*)&myrow[4 * j] = make_float4(fmaxf(v.x, 0.f), fmaxf(v.y, 0.f),
                                              fmaxf(v.z, 0.f), fmaxf(v.w, 0.f));
    }
    __syncthreads();
    float4* o4 = (float4*)h1;
    #pragma unroll
    for (int r = 0; r < 16; r++) {
        int idx = r * D1_BLK + threadIdx.x;
        int row = idx >> 4, col = idx & 15;
        int gn = n0 + row;
        if (gn < N) o4[(size_t)gn * 16 + col] = *(float4*)&lds[row * D1_PAD + col * 4];
    }
}

// ----------------------------- dense2res -----------------------------------

#define D2_BLK 128
#define D2_PAD 68

__global__ __launch_bounds__(D2_BLK) void dense2res_k(const float* __restrict__ h1,
                                                      const float* __restrict__ W2,
                                                      const float* __restrict__ b2,
                                                      const float* __restrict__ Wres,
                                                      const float* __restrict__ bres,
                                                      const float* __restrict__ Wattn,
                                                      const float* __restrict__ dinv,
                                                      float* __restrict__ hg,
                                                      float2* __restrict__ hs2,
                                                      float* __restrict__ resg,
                                                      float* __restrict__ thv, int N) {
    __shared__ float lds[D2_BLK * D2_PAD];
    int n0 = blockIdx.x * D2_BLK;
    int n = n0 + threadIdx.x;
    bool act = (n < N);
    const float4* W = (const float4*)W2;
    const float4* B = (const float4*)b2;
    float4 acc[16];
    #pragma unroll
    for (int j = 0; j < 16; j++) acc[j] = B[j];
    if (act) {
        const float4* X = (const float4*)h1 + (size_t)n * 16;
        float4 a = X[0];
        #pragma unroll 1
        for (int kc = 0; kc < 16; kc++) {
            float4 an = a;
            if (kc + 1 < 16) an = X[kc + 1];
            const float4* wrow = W + kc * 64;
            #pragma unroll
            for (int j = 0; j < 16; j++) {
                fma4(acc[j], a.x, wrow[j]);
                fma4(acc[j], a.y, wrow[16 + j]);
                fma4(acc[j], a.z, wrow[32 + j]);
                fma4(acc[j], a.w, wrow[48 + j]);
            }
            a = an;
        }
    }
    const float4* Wa = (const float4*)Wattn;
    float th = 0.f;
    float* myrow = &lds[threadIdx.x * D2_PAD];
    #pragma unroll
    for (int j = 0; j < 16; j++) {
        float4 v = acc[j];
        v.x = fmaxf(v.x, 0.f); v.y = fmaxf(v.y, 0.f);
        v.z = fmaxf(v.z, 0.f); v.w = fmaxf(v.w, 0.f);
        acc[j] = v;
        *(float4*)&myrow[4 * j] = v;
        float4 w = Wa[j];
        th += v.x * w.x + v.y * w.y + v.z * w.z + v.w * w.w;
    }
    if (act) thv[n] = th;
    __syncthreads();
    float4* h4 = (float4*)hg;
    #pragma unroll
    for (int r = 0; r < 16; r++) {
        int idx = r * D2_BLK + threadIdx.x;
        int row = idx >> 4, col = idx & 15;
        int gn = n0 + row;
        if (gn < N) {
            float4 v = *(float4*)&lds[row * D2_PAD + col * 4];
            h4[(size_t)gn * 16 + col] = v;
            float di = dinv[gn];
            hs2[(size_t)gn * 16 + col] =
                pack_half4(v.x * di, v.y * di, v.z * di, v.w * di);
        }
    }
    // res = h @ Wres + bres (h still in regs)
    const float4* WR = (const float4*)Wres;
    const float4* BR = (const float4*)bres;
    float4 acc2[16];
    #pragma unroll
    for (int j = 0; j < 16; j++) acc2[j] = BR[j];
    #pragma unroll 1
    for (int kc = 0; kc < 16; kc++) {
        float4 a2 = acc[kc];
        const float4* wrow = WR + kc * 64;
        #pragma unroll
        for (int j = 0; j < 16; j++) {
            fma4(acc2[j], a2.x, wrow[j]);
            fma4(acc2[j], a2.y, wrow[16 + j]);
            fma4(acc2[j], a2.z, wrow[32 + j]);
            fma4(acc2[j], a2.w, wrow[48 + j]);
        }
    }
    __syncthreads();
    #pragma unroll
    for (int j = 0; j < 16; j++) *(float4*)&myrow[4 * j] = acc2[j];
    __syncthreads();
    float4* r4 = (float4*)resg;
    #pragma unroll
    for (int r = 0; r < 16; r++) {
        int idx = r * D2_BLK + threadIdx.x;
        int row = idx >> 4, col = idx & 15;
        int gn = n0 + row;
        if (gn < N) r4[(size_t)gn * 16 + col] = *(float4*)&lds[row * D2_PAD + col * 4];
    }
}

// ----------------------------- SPMM (spmm1) --------------------------------
// Wave per node (4/block). Rotated-index gather: next iteration's srcs load
// during current gathers; gather addrs register-ready at iteration start.

__global__ __launch_bounds__(256) void spmm_k(const float2* __restrict__ xs,
                                              const int* __restrict__ srcs,
                                              const int* __restrict__ rowPtr,
                                              const float* __restrict__ dinv,
                                              const float* __restrict__ Wattn,
                                              float4* __restrict__ u,
                                              float2* __restrict__ us,
                                              float* __restrict__ tav, int N) {
    int node = (blockIdx.x * 256 + threadIdx.x) >> 6;
    if (node >= N) return;
    int lane = threadIdx.x & 63;
    int sub = lane >> 4;
    int q = lane & 15;
    int s0 = rowPtr[node], s1 = rowPtr[node + 1];
    float4 a0 = make_float4(0.f, 0.f, 0.f, 0.f);
    int i = s0 + sub;
    if (i + 12 < s1) {
        int cA = srcs[i], cB = srcs[i + 4], cC = srcs[i + 8], cD = srcs[i + 12];
        i += 16;
        for (; i + 12 < s1; i += 16) {
            int nA = srcs[i], nB = srcs[i + 4], nC = srcs[i + 8], nD = srcs[i + 12];
            float2 vA = xs[(size_t)cA * 16 + q];
            float2 vB = xs[(size_t)cB * 16 + q];
            float2 vC = xs[(size_t)cC * 16 + q];
            float2 vD = xs[(size_t)cD * 16 + q];
            accq(a0, vA, vB, vC, vD);
            cA = nA; cB = nB; cC = nC; cD = nD;
        }
        float2 vA = xs[(size_t)cA * 16 + q];
        float2 vB = xs[(size_t)cB * 16 + q];
        float2 vC = xs[(size_t)cC * 16 + q];
        float2 vD = xs[(size_t)cD * 16 + q];
        accq(a0, vA, vB, vC, vD);
    }
    for (; i + 4 < s1; i += 8) {
        int sA = srcs[i];
        int sB = srcs[i + 4];
        float2 vA = xs[(size_t)sA * 16 + q];
        float2 vB = xs[(size_t)sB * 16 + q];
        accd(a0, vA, vB);
    }
    if (i < s1) {
        float2 vA = xs[(size_t)srcs[i] * 16 + q];
        acch4(a0, vA);
    }
    #pragma unroll
    for (int m = 16; m < 64; m <<= 1) {
        a0.x += __shfl_xor(a0.x, m, 64);
        a0.y += __shfl_xor(a0.y, m, 64);
        a0.z += __shfl_xor(a0.z, m, 64);
        a0.w += __shfl_xor(a0.w, m, 64);
    }
    if (sub == 0) {
        float di = dinv[node];
        float4 r = make_float4(a0.x * di, a0.y * di, a0.z * di, a0.w * di);
        u[(size_t)node * 16 + q] = r;
        us[(size_t)node * 16 + q] =
            pack_half4(r.x * di, r.y * di, r.z * di, r.w * di);
        float4 w = ((const float4*)Wattn)[q];
        float p = r.x * w.x + r.y * w.y + r.z * w.z + r.w * w.w;
        #pragma unroll
        for (int m = 1; m < 16; m <<= 1) p += __shfl_xor(p, m, 64);
        if (lane == 0) tav[node] = p;
    }
}

// ----------------------------- fused spmm2 + tail --------------------------
// Wave per node (4/block), no block barrier. Rotated-index gather; hoisted
// node-row loads; dot2 GEMVs against L1-resident fp16 weights.

#define TL_PAD 68
#define BS_HPAD 136

__global__ __launch_bounds__(256) void tail_k(const float2* __restrict__ u1s,
                                              const int* __restrict__ srcs,
                                              const int* __restrict__ rowPtr,
                                              const float* __restrict__ dinv,
                                              const float* __restrict__ hg,
                                              const float* __restrict__ u1g,
                                              const float* __restrict__ resg,
                                              const float* __restrict__ thv,
                                              const float* __restrict__ tav,
                                              const float* __restrict__ Wattn,
                                              const float* __restrict__ battn,
                                              const unsigned int* __restrict__ Wf1h,
                                              const float* __restrict__ bf1,
                                              const float* __restrict__ Wf2,
                                              const float* __restrict__ bf2,
                                              const unsigned int* __restrict__ W3h,
                                              const float* __restrict__ b3,
                                              const float* __restrict__ W4,
                                              const float* __restrict__ b4,
                                              float2* __restrict__ out, int N) {
    __shared__ float lds[4 * TL_PAD];
    __shared__ _Float16 bsl[4 * BS_HPAD];
    int w = threadIdx.x >> 6;
    int lane = threadIdx.x & 63;
    int node = blockIdx.x * 4 + w;
    if (node >= N) return;
    int sub = lane >> 4, q = lane & 15;
    // hoisted independent loads: in flight during the gather below
    float hj = hg[(size_t)node * 64 + lane];
    float u1j = u1g[(size_t)node * 64 + lane];
    float resj = resg[(size_t)node * 64 + lane];
    float th = thv[node], ta = tav[node], ba = battn[0];
    float waj = Wattn[lane];
    float dinv_n = dinv[node];
    {
        int s0 = rowPtr[node], s1 = rowPtr[node + 1];
        float4 a0 = make_float4(0.f, 0.f, 0.f, 0.f);
        int i = s0 + sub;
        if (i + 12 < s1) {
            int cA = srcs[i], cB = srcs[i + 4], cC = srcs[i + 8], cD = srcs[i + 12];
            i += 16;
            for (; i + 12 < s1; i += 16) {
                int nA = srcs[i], nB = srcs[i + 4], nC = srcs[i + 8], nD = srcs[i + 12];
                float2 vA = u1s[(size_t)cA * 16 + q];
                float2 vB = u1s[(size_t)cB * 16 + q];
                float2 vC = u1s[(size_t)cC * 16 + q];
                float2 vD = u1s[(size_t)cD * 16 + q];
                accq(a0, vA, vB, vC, vD);
                cA = nA; cB = nB; cC = nC; cD = nD;
            }
            float2 vA = u1s[(size_t)cA * 16 + q];
            float2 vB = u1s[(size_t)cB * 16 + q];
            float2 vC = u1s[(size_t)cC * 16 + q];
            float2 vD = u1s[(size_t)cD * 16 + q];
            accq(a0, vA, vB, vC, vD);
        }
        for (; i + 4 < s1; i += 8) {
            int sA = srcs[i];
            int sB = srcs[i + 4];
            float2 vA = u1s[(size_t)sA * 16 + q];
            float2 vB = u1s[(size_t)sB * 16 + q];
            accd(a0, vA, vB);
        }
        if (i < s1) {
            float2 vA = u1s[(size_t)srcs[i] * 16 + q];
            acch4(a0, vA);
        }
        #pragma unroll
        for (int m = 16; m < 64; m <<= 1) {
            a0.x += __shfl_xor(a0.x, m, 64);
            a0.y += __shfl_xor(a0.y, m, 64);
            a0.z += __shfl_xor(a0.z, m, 64);
            a0.w += __shfl_xor(a0.w, m, 64);
        }
        if (sub == 0) {
            *(float4*)&lds[w * TL_PAD + q * 4] =
                make_float4(a0.x * dinv_n, a0.y * dinv_n,
                            a0.z * dinv_n, a0.w * dinv_n);
        }
    }
    // wave-private LDS: same wave wrote it; DS ops in-order per wave.
    float u2j = lds[w * TL_PAD + lane];                  // feature j = lane
    // tb = u2 . Wattn
    float tb = u2j * waj;
    #pragma unroll
    for (int m = 1; m < 64; m <<= 1) tb += __shfl_xor(tb, m, 64);
    float s0 = 0.75f * th + 1.5f * ta + 0.75f * tb + ba;
    float s1 = 1.5f * th - 1.5f * tb + ba;
    float s2 = 0.75f * th - 1.5f * ta + 0.75f * tb + ba;
    float mx = fmaxf(s0, fmaxf(s1, s2));
    float e0 = expf(s0 - mx), e1 = expf(s1 - mx), e2 = expf(s2 - mx);
    float inv = 1.f / (e0 + e1 + e2);
    float w0 = e0 * inv, w1 = e1 * inv, w2 = e2 * inv;
    float ca = 0.75f * w0 + 1.5f * w1 + 0.75f * w2;
    float cb = 1.5f * (w0 - w2);
    float cc = 0.75f * w0 - 1.5f * w1 + 0.75f * w2;
    float afj = ca * hj + cb * u1j + cc * u2j;
    // stage af | h as fp16 into the wave's broadcast slice
    _Float16* bsh = &bsl[w * BS_HPAD];
    bsh[lane] = (_Float16)afj;
    bsh[64 + lane] = (_Float16)hj;
    // t = relu([af|h] @ Wf1 + bf1): dot2 GEMV over 64 packed pairs
    float t0 = bf1[lane], t1 = 0.f, t2 = 0.f, t3 = 0.f;
    #pragma unroll 1
    for (int kk = 0; kk < 64; kk += 4) {
        uint4 br = *(const uint4*)&bsh[2 * kk];   // pairs kk..kk+3 (16B)
        unsigned int w0_ = Wf1h[(kk + 0) * 64 + lane];
        unsigned int w1_ = Wf1h[(kk + 1) * 64 + lane];
        unsigned int w2_ = Wf1h[(kk + 2) * 64 + lane];
        unsigned int w3_ = Wf1h[(kk + 3) * 64 + lane];
        t0 = __builtin_amdgcn_fdot2(as_h2(br.x), as_h2(w0_), t0, false);
        t1 = __builtin_amdgcn_fdot2(as_h2(br.y), as_h2(w1_), t1, false);
        t2 = __builtin_amdgcn_fdot2(as_h2(br.z), as_h2(w2_), t2, false);
        t3 = __builtin_amdgcn_fdot2(as_h2(br.w), as_h2(w3_), t3, false);
    }
    float t = fmaxf((t0 + t1) + (t2 + t3), 0.f);
    float fwacc = t * Wf2[lane];
    #pragma unroll
    for (int m = 1; m < 64; m <<= 1) fwacc += __shfl_xor(fwacc, m, 64);
    float fw = 1.f / (1.f + expf(-(fwacc + bf2[0])));
    // fused = 0.1*fw*af + (1-fw)*h + 0.8*res   (mean_fused == h exactly)
    float fj = 0.1f * fw * afj + (1.f - fw) * hj + 0.8f * resj;
    bsh[lane] = (_Float16)fj;   // overwrite af slot (in-order DS)
    float g0 = b3[lane], g1 = 0.f, g2 = 0.f, g3 = 0.f;
    #pragma unroll 1
    for (int kk = 0; kk < 32; kk += 4) {
        uint4 br = *(const uint4*)&bsh[2 * kk];   // pairs kk..kk+3
        unsigned int w0_ = W3h[(kk + 0) * 64 + lane];
        unsigned int w1_ = W3h[(kk + 1) * 64 + lane];
        unsigned int w2_ = W3h[(kk + 2) * 64 + lane];
        unsigned int w3_ = W3h[(kk + 3) * 64 + lane];
        g0 = __builtin_amdgcn_fdot2(as_h2(br.x), as_h2(w0_), g0, false);
        g1 = __builtin_amdgcn_fdot2(as_h2(br.y), as_h2(w1_), g1, false);
        g2 = __builtin_amdgcn_fdot2(as_h2(br.z), as_h2(w2_), g2, false);
        g3 = __builtin_amdgcn_fdot2(as_h2(br.w), as_h2(w3_), g3, false);
    }
    float g = fmaxf((g0 + g1) + (g2 + g3), 0.f);
    float2 w4 = ((const float2*)W4)[lane];
    float l0 = g * w4.x, l1 = g * w4.y;
    #pragma unroll
    for (int m = 1; m < 64; m <<= 1) {
        l0 += __shfl_xor(l0, m, 64);
        l1 += __shfl_xor(l1, m, 64);
    }
    if (lane == 0) out[node] = make_float2(l0 + b4[0], l1 + b4[1]);
}

// ----------------------------- launch --------------------------------------

extern "C" void kernel_launch(void* const* d_in, const int* in_sizes, int n_in,
                              void* d_out, int out_size, void* d_ws, size_t ws_size,
                              hipStream_t stream) {
    const float* in_feat = (const float*)d_in[0];
    const int*   src     = (const int*)d_in[1];
    const int*   dst     = (const int*)d_in[2];
    const float* W1   = (const float*)d_in[3];
    const float* b1   = (const float*)d_in[4];
    const float* W2   = (const float*)d_in[5];
    const float* b2   = (const float*)d_in[6];
    const float* Wres = (const float*)d_in[7];
    const float* bres = (const float*)d_in[8];
    const float* Wattn = (const float*)d_in[9];
    const float* battn = (const float*)d_in[10];
    const float* Wf1  = (const float*)d_in[11];
    const float* bf1  = (const float*)d_in[12];
    const float* Wf2  = (const float*)d_in[13];
    const float* bf2  = (const float*)d_in[14];
    const float* W3   = (const float*)d_in[15];
    const float* b3   = (const float*)d_in[16];
    const float* W4   = (const float*)d_in[17];
    const float* b4   = (const float*)d_in[18];

    const int N = in_sizes[0] / 128;
    const int E = in_sizes[1];
    const int B = (N + BNODES - 1) >> BSHIFT;

    char* p = (char*)d_ws;
    auto take = [&](size_t bytes) -> char* {
        char* r = p;
        p += (bytes + 255) & ~(size_t)255;
        return r;
    };
    int*   bucketCount  = (int*)take((size_t)(B + 1) * 4);
    int*   bucketPtr    = (int*)take((size_t)(B + 1) * 4);
    int*   bucketCursor = (int*)take((size_t)(B + 1) * 4);
    int*   rowPtr       = (int*)take((size_t)(N + 1) * 4);
    float* dinv         = (float*)take((size_t)N * 4);
    int*   srcSorted    = (int*)take((size_t)E * 4);
    float* thv          = (float*)take((size_t)N * 4);
    float* tav          = (float*)take((size_t)N * 4);
    unsigned int* Wf1h  = (unsigned int*)take((size_t)64 * 64 * 4);
    unsigned int* W3h   = (unsigned int*)take((size_t)32 * 64 * 4);
    float* h1  = (float*)take((size_t)N * 256);
    float* h   = (float*)take((size_t)N * 256);
    float* hs  = (float*)take((size_t)N * 128);   // f16 packed, 64 halves/row
    float* res = (float*)take((size_t)N * 256);
    float* u1  = (float*)take((size_t)N * 256);
    float* u1s = (float*)take((size_t)N * 128);   // f16 packed
    int*   ebuf = (int*)h1;   // dead before dense1 writes h1 (stream order)

    int eb = (E + CHUNK - 1) / CHUNK;
    int d1b = (N + D1_BLK - 1) / D1_BLK;
    int d2b = (N + D2_BLK - 1) / D2_BLK;
    int spb = (N * 64 + 255) / 256;
    int tlb = (N + 3) / 4;

    pack_w_k<<<24, 256, 0, stream>>>(Wf1, W3, Wf1h, W3h);

    hipMemsetAsync(bucketCount, 0, (size_t)B * 4, stream);
    bucket_count_k<<<eb, 256, 0, stream>>>(dst, bucketCount, E, B);
    bucket_scan_k<<<1, 64, 0, stream>>>(bucketCount, bucketPtr, bucketCursor,
                                        rowPtr, B, N, E);
    bucket_scatter_k<<<eb, 256, 0, stream>>>(src, dst, bucketCursor, ebuf, E, B);
    csr_build_k<<<B, 256, 0, stream>>>(ebuf, bucketPtr, rowPtr, dinv, srcSorted, N);

    dense1_k<<<d1b, D1_BLK, 0, stream>>>(in_feat, W1, b1, h1, N);
    dense2res_k<<<d2b, D2_BLK, 0, stream>>>(h1, W2, b2, Wres, bres, Wattn, dinv,
                                            h, (float2*)hs, res, thv, N);

    spmm_k<<<spb, 256, 0, stream>>>((const float2*)hs, srcSorted, rowPtr, dinv,
                                    Wattn, (float4*)u1, (float2*)u1s, tav, N);

    tail_k<<<tlb, 256, 0, stream>>>((const float2*)u1s, srcSorted, rowPtr, dinv,
                                    h, u1, res, thv, tav, Wattn, battn,
                                    Wf1h, bf1, Wf2, bf2, W3h, b3, W4, b4,
                                    (float2*)d_out, N);
}

// Round 11
// 344.382 us; speedup vs baseline: 1.0737x; 1.0520x over previous
//
#include <hip/hip_runtime.h>
#include <hip/hip_fp16.h>
#include <math.h>

// ---------------------------------------------------------------------------
// ADCGNN amazon: N=50000, E=1.6M, IN=128, H=64, C=2, K=3
//
// R11: LDS-broadcast GEMVs -> L1 weight thrash found. [391]
// R12: fp16 dot2 GEMVs (24KB weights fit L1): tail 122->89. [367]
// R13: pk-tree accumulate: VALU 43%, flat -> ~45us gather latency floor.
// R14: src-index rotation: tail 89.5->84. [362 best]
// R15 (this round): grid-concat fusion of independent kernels. Build chain
//     (count/scatter) is data-independent of dense chain (dense1/dense2res)
//     until spmm; streams/events banned -> co-schedule via one launch with
//     blockIdx branching. dense kernels reworked to 256 nodes/block with
//     half-row LDS rounds (36KB). ebuf de-aliased from h1 (now concurrent).
//
// Pipeline:
//   K1: bucket_count || dense1 || pack_w
//   K2: bucket_scan
//   K3: bucket_scatter || dense2res
//   csr_build
//   spmm1 (rotated-index gather)
//   tail  (rotated gather + softmax + dot2 GEMVs)
// ---------------------------------------------------------------------------

#define BSHIFT 7
#define BNODES 128
#define BMAX   512
#define EPT    32
#define CHUNK  (256 * EPT)
#define CAP    8192

typedef _Float16 h2v __attribute__((ext_vector_type(2)));

__device__ __forceinline__ h2v as_h2(unsigned int u) {
    union { unsigned int u; h2v h; } c; c.u = u; return c.h;
}

__device__ __forceinline__ void fma4(float4& acc, float s, const float4 w) {
    acc.x += s * w.x; acc.y += s * w.y; acc.z += s * w.z; acc.w += s * w.w;
}

__device__ __forceinline__ float2 pack_half4(float x, float y, float z, float w) {
    union { __half2 h[2]; float2 f; } u;
    u.h[0] = __floats2half2_rn(x, y);
    u.h[1] = __floats2half2_rn(z, w);
    return u.f;
}

__device__ __forceinline__ void acch4(float4& a, float2 p) {
    union { float2 f; __half2 h[2]; } u; u.f = p;
    float2 lo = __half22float2(u.h[0]);
    float2 hi = __half22float2(u.h[1]);
    a.x += lo.x; a.y += lo.y; a.z += hi.x; a.w += hi.y;
}

// depth-2 fp16 pairwise tree over 4 edges, then fp32 accumulate.
__device__ __forceinline__ void accq(float4& a, float2 pA, float2 pB,
                                     float2 pC, float2 pD) {
    union { float2 f; __half2 h[2]; } A, B, C, D;
    A.f = pA; B.f = pB; C.f = pC; D.f = pD;
    __half2 s0 = __hadd2(__hadd2(A.h[0], B.h[0]), __hadd2(C.h[0], D.h[0]));
    __half2 s1 = __hadd2(__hadd2(A.h[1], B.h[1]), __hadd2(C.h[1], D.h[1]));
    float2 lo = __half22float2(s0), hi = __half22float2(s1);
    a.x += lo.x; a.y += lo.y; a.z += hi.x; a.w += hi.y;
}

__device__ __forceinline__ void accd(float4& a, float2 pA, float2 pB) {
    union { float2 f; __half2 h[2]; } A, B;
    A.f = pA; B.f = pB;
    __half2 s0 = __hadd2(A.h[0], B.h[0]);
    __half2 s1 = __hadd2(A.h[1], B.h[1]);
    float2 lo = __half22float2(s0), hi = __half22float2(s1);
    a.x += lo.x; a.y += lo.y; a.z += hi.x; a.w += hi.y;
}

// ----------------------------- K1: count || dense1 || pack_w ---------------
// smem: count uses 2KB of it; dense1 uses 36KB (256 rows x 36 floats).

__global__ __launch_bounds__(256) void fused1_k(const int* __restrict__ dst,
                                                int* __restrict__ bucketCount,
                                                int E, int B,
                                                const float* __restrict__ Xg,
                                                const float* __restrict__ W1,
                                                const float* __restrict__ b1,
                                                float* __restrict__ h1, int N,
                                                const float* __restrict__ Wf1,
                                                const float* __restrict__ W3,
                                                unsigned int* __restrict__ Wf1h,
                                                unsigned int* __restrict__ W3h,
                                                int eb, int d1b) {
    __shared__ float smem[256 * 36];
    int bid = blockIdx.x;
    if (bid < eb) {
        // ---- bucket_count ----
        int* cnt = (int*)smem;
        for (int i = threadIdx.x; i < B; i += 256) cnt[i] = 0;
        __syncthreads();
        int base = bid * CHUNK;
        #pragma unroll
        for (int t = 0; t < EPT; t++) {
            int e = base + t * 256 + threadIdx.x;
            if (e < E) atomicAdd(&cnt[dst[e] >> BSHIFT], 1);
        }
        __syncthreads();
        for (int i = threadIdx.x; i < B; i += 256)
            if (cnt[i] > 0) atomicAdd(&bucketCount[i], cnt[i]);
        return;
    }
    bid -= eb;
    if (bid < d1b) {
        // ---- dense1: 256 nodes/block, two half-row LDS rounds ----
        int n0 = bid * 256;
        int n = n0 + threadIdx.x;
        bool act = (n < N);
        const float4* W = (const float4*)W1;
        const float4* Bb = (const float4*)b1;
        float4 acc[16];
        #pragma unroll
        for (int j = 0; j < 16; j++) acc[j] = Bb[j];
        if (act) {
            const float4* X = (const float4*)Xg + (size_t)n * 32;
            float4 a = X[0];
            #pragma unroll 1
            for (int kc = 0; kc < 32; kc++) {
                float4 an = a;
                if (kc + 1 < 32) an = X[kc + 1];
                const float4* wrow = W + kc * 64;
                #pragma unroll
                for (int j = 0; j < 16; j++) {
                    fma4(acc[j], a.x, wrow[j]);
                    fma4(acc[j], a.y, wrow[16 + j]);
                    fma4(acc[j], a.z, wrow[32 + j]);
                    fma4(acc[j], a.w, wrow[48 + j]);
                }
                a = an;
            }
        }
        #pragma unroll
        for (int j = 0; j < 16; j++) {
            float4 v = acc[j];
            acc[j] = make_float4(fmaxf(v.x, 0.f), fmaxf(v.y, 0.f),
                                 fmaxf(v.z, 0.f), fmaxf(v.w, 0.f));
        }
        float4* o4 = (float4*)h1;
        #pragma unroll
        for (int r2 = 0; r2 < 2; r2++) {
            __syncthreads();
            float* myrow = &smem[threadIdx.x * 36];
            #pragma unroll
            for (int j = 0; j < 8; j++) *(float4*)&myrow[4 * j] = acc[r2 * 8 + j];
            __syncthreads();
            #pragma unroll
            for (int r = 0; r < 8; r++) {
                int idx = r * 256 + threadIdx.x;
                int row = idx >> 3, col = idx & 7;
                int gn = n0 + row;
                if (gn < N)
                    o4[(size_t)gn * 16 + r2 * 8 + col] =
                        *(float4*)&smem[row * 36 + col * 4];
            }
        }
        return;
    }
    bid -= d1b;
    // ---- pack_w ----
    int t = bid * 256 + threadIdx.x;
    if (t < 64 * 64) {
        int kk = t >> 6, j = t & 63;
        union { __half2 h; unsigned int u; } c;
        c.h = __floats2half2_rn(Wf1[(2 * kk) * 64 + j], Wf1[(2 * kk + 1) * 64 + j]);
        Wf1h[t] = c.u;
    } else if (t < 64 * 64 + 32 * 64) {
        int r = t - 64 * 64;
        int kk = r >> 6, j = r & 63;
        union { __half2 h; unsigned int u; } c;
        c.h = __floats2half2_rn(W3[(2 * kk) * 64 + j], W3[(2 * kk + 1) * 64 + j]);
        W3h[r] = c.u;
    }
}

// ----------------------------- K2: bucket_scan ------------------------------

__global__ __launch_bounds__(64) void bucket_scan_k(const int* __restrict__ bucketCount,
                                                    int* __restrict__ bucketPtr,
                                                    int* __restrict__ bucketCursor,
                                                    int* __restrict__ rowPtr,
                                                    int B, int N, int E) {
    int lane = threadIdx.x;
    const int PT = (BMAX + 63) / 64;
    int v[PT]; int s = 0;
    #pragma unroll
    for (int t = 0; t < PT; t++) {
        int i = lane * PT + t;
        v[t] = (i < B) ? bucketCount[i] : 0;
        s += v[t];
    }
    int x = s;
    #pragma unroll
    for (int off = 1; off < 64; off <<= 1) {
        int y = __shfl_up(x, off, 64);
        if (lane >= off) x += y;
    }
    int run = x - s;
    #pragma unroll
    for (int t = 0; t < PT; t++) {
        int i = lane * PT + t;
        if (i < B) { bucketPtr[i] = run; bucketCursor[i] = run; }
        run += v[t];
    }
    if (lane == 63) bucketPtr[B] = x;
    if (lane == 0) rowPtr[N] = E;
}

// ----------------------------- K3: scatter || dense2res ---------------------

__global__ __launch_bounds__(256) void fused3_k(const int* __restrict__ src,
                                                const int* __restrict__ dst,
                                                int* __restrict__ bucketCursor,
                                                int* __restrict__ ebuf,
                                                int E, int B,
                                                const float* __restrict__ h1,
                                                const float* __restrict__ W2,
                                                const float* __restrict__ b2,
                                                const float* __restrict__ Wres,
                                                const float* __restrict__ bres,
                                                const float* __restrict__ Wattn,
                                                const float* __restrict__ dinv,
                                                float* __restrict__ hg,
                                                float2* __restrict__ hs2,
                                                float* __restrict__ resg,
                                                float* __restrict__ thv, int N,
                                                int eb, int d2b) {
    __shared__ float smem[256 * 36];
    int bid = blockIdx.x;
    if (bid < eb) {
        // ---- bucket_scatter ----
        int* cnt = (int*)smem;
        int* base = cnt + BMAX;
        int* cur = base + BMAX;
        for (int i = threadIdx.x; i < B; i += 256) { cnt[i] = 0; cur[i] = 0; }
        __syncthreads();
        int cbase = bid * CHUNK;
        int d[EPT];
        #pragma unroll
        for (int t = 0; t < EPT; t++) {
            int e = cbase + t * 256 + threadIdx.x;
            d[t] = (e < E) ? dst[e] : -1;
            if (d[t] >= 0) atomicAdd(&cnt[d[t] >> BSHIFT], 1);
        }
        __syncthreads();
        for (int i = threadIdx.x; i < B; i += 256)
            if (cnt[i] > 0) base[i] = atomicAdd(&bucketCursor[i], cnt[i]);
        __syncthreads();
        #pragma unroll
        for (int t = 0; t < EPT; t++) {
            int e = cbase + t * 256 + threadIdx.x;
            if (d[t] >= 0) {
                int b = d[t] >> BSHIFT;
                int c = atomicAdd(&cur[b], 1);
                int pack = (src[e] & 0xFFFF) | ((d[t] & (BNODES - 1)) << 16);
                ebuf[base[b] + c] = pack;
            }
        }
        return;
    }
    bid -= eb;
    // ---- dense2res: 256 nodes/block, half-row LDS rounds ----
    int n0 = bid * 256;
    int n = n0 + threadIdx.x;
    bool act = (n < N);
    const float4* W = (const float4*)W2;
    const float4* Bb = (const float4*)b2;
    float4 acc[16];
    #pragma unroll
    for (int j = 0; j < 16; j++) acc[j] = Bb[j];
    if (act) {
        const float4* X = (const float4*)h1 + (size_t)n * 16;
        float4 a = X[0];
        #pragma unroll 1
        for (int kc = 0; kc < 16; kc++) {
            float4 an = a;
            if (kc + 1 < 16) an = X[kc + 1];
            const float4* wrow = W + kc * 64;
            #pragma unroll
            for (int j = 0; j < 16; j++) {
                fma4(acc[j], a.x, wrow[j]);
                fma4(acc[j], a.y, wrow[16 + j]);
                fma4(acc[j], a.z, wrow[32 + j]);
                fma4(acc[j], a.w, wrow[48 + j]);
            }
            a = an;
        }
    }
    const float4* Wa = (const float4*)Wattn;
    float th = 0.f;
    #pragma unroll
    for (int j = 0; j < 16; j++) {
        float4 v = acc[j];
        v.x = fmaxf(v.x, 0.f); v.y = fmaxf(v.y, 0.f);
        v.z = fmaxf(v.z, 0.f); v.w = fmaxf(v.w, 0.f);
        acc[j] = v;
        float4 w = Wa[j];
        th += v.x * w.x + v.y * w.y + v.z * w.z + v.w * w.w;
    }
    if (act) thv[n] = th;
    // h + hs rounds
    float4* h4 = (float4*)hg;
    #pragma unroll
    for (int r2 = 0; r2 < 2; r2++) {
        __syncthreads();
        float* myrow = &smem[threadIdx.x * 36];
        #pragma unroll
        for (int j = 0; j < 8; j++) *(float4*)&myrow[4 * j] = acc[r2 * 8 + j];
        __syncthreads();
        #pragma unroll
        for (int r = 0; r < 8; r++) {
            int idx = r * 256 + threadIdx.x;
            int row = idx >> 3, col = idx & 7;
            int gn = n0 + row;
            if (gn < N) {
                float4 v = *(float4*)&smem[row * 36 + col * 4];
                h4[(size_t)gn * 16 + r2 * 8 + col] = v;
                float di = dinv[gn];
                hs2[(size_t)gn * 16 + r2 * 8 + col] =
                    pack_half4(v.x * di, v.y * di, v.z * di, v.w * di);
            }
        }
    }
    // res = h @ Wres + bres (h still in regs)
    const float4* WR = (const float4*)Wres;
    const float4* BR = (const float4*)bres;
    float4 acc2[16];
    #pragma unroll
    for (int j = 0; j < 16; j++) acc2[j] = BR[j];
    #pragma unroll 1
    for (int kc = 0; kc < 16; kc++) {
        float4 a2 = acc[kc];
        const float4* wrow = WR + kc * 64;
        #pragma unroll
        for (int j = 0; j < 16; j++) {
            fma4(acc2[j], a2.x, wrow[j]);
            fma4(acc2[j], a2.y, wrow[16 + j]);
            fma4(acc2[j], a2.z, wrow[32 + j]);
            fma4(acc2[j], a2.w, wrow[48 + j]);
        }
    }
    float4* r4 = (float4*)resg;
    #pragma unroll
    for (int r2 = 0; r2 < 2; r2++) {
        __syncthreads();
        float* myrow = &smem[threadIdx.x * 36];
        #pragma unroll
        for (int j = 0; j < 8; j++) *(float4*)&myrow[4 * j] = acc2[r2 * 8 + j];
        __syncthreads();
        #pragma unroll
        for (int r = 0; r < 8; r++) {
            int idx = r * 256 + threadIdx.x;
            int row = idx >> 3, col = idx & 7;
            int gn = n0 + row;
            if (gn < N)
                r4[(size_t)gn * 16 + r2 * 8 + col] =
                    *(float4*)&smem[row * 36 + col * 4];
        }
    }
}

// ----------------------------- csr_build ------------------------------------

__global__ __launch_bounds__(256) void csr_build_k(const int* __restrict__ ebuf,
                                                   const int* __restrict__ bucketPtr,
                                                   int* __restrict__ rowPtr,
                                                   float* __restrict__ dinv,
                                                   int* __restrict__ srcSorted,
                                                   int N) {
    __shared__ int deg[BNODES];
    __shared__ int rp[BNODES + 1];
    __shared__ int cur[BNODES];
    __shared__ int stage[CAP];
    int b = blockIdx.x;
    int nodeBase = b << BSHIFT;
    int nNodes = min(BNODES, N - nodeBase);
    int eBase = bucketPtr[b];
    int eCnt = bucketPtr[b + 1] - eBase;
    for (int i = threadIdx.x; i < BNODES; i += 256) deg[i] = 0;
    __syncthreads();
    for (int i = threadIdx.x; i < eCnt; i += 256)
        atomicAdd(&deg[(ebuf[eBase + i] >> 16) & (BNODES - 1)], 1);
    __syncthreads();
    if (threadIdx.x < 64) {
        int lane = threadIdx.x;
        int d0 = deg[2 * lane], d1 = deg[2 * lane + 1];
        int s = d0 + d1;
        int x = s;
        #pragma unroll
        for (int off = 1; off < 64; off <<= 1) {
            int y = __shfl_up(x, off, 64);
            if (lane >= off) x += y;
        }
        int ex = x - s;
        rp[2 * lane] = ex;
        rp[2 * lane + 1] = ex + d0;
        cur[2 * lane] = ex;
        cur[2 * lane + 1] = ex + d0;
        if (lane == 63) rp[BNODES] = x;
    }
    __syncthreads();
    for (int j = threadIdx.x; j < nNodes; j += 256) {
        rowPtr[nodeBase + j] = eBase + rp[j];
        int dg = deg[j];
        dinv[nodeBase + j] = rsqrtf((float)(dg > 1 ? dg : 1));
    }
    if (eCnt <= CAP) {
        for (int i = threadIdx.x; i < eCnt; i += 256) {
            int p = ebuf[eBase + i];
            int ld = (p >> 16) & (BNODES - 1);
            int pos = atomicAdd(&cur[ld], 1);
            stage[pos] = p & 0xFFFF;
        }
        __syncthreads();
        for (int i = threadIdx.x; i < eCnt; i += 256)
            srcSorted[eBase + i] = stage[i];
    } else {
        for (int i = threadIdx.x; i < eCnt; i += 256) {
            int p = ebuf[eBase + i];
            int ld = (p >> 16) & (BNODES - 1);
            int pos = atomicAdd(&cur[ld], 1);
            srcSorted[eBase + pos] = p & 0xFFFF;
        }
    }
}

// ----------------------------- SPMM (spmm1) --------------------------------

__global__ __launch_bounds__(256) void spmm_k(const float2* __restrict__ xs,
                                              const int* __restrict__ srcs,
                                              const int* __restrict__ rowPtr,
                                              const float* __restrict__ dinv,
                                              const float* __restrict__ Wattn,
                                              float4* __restrict__ u,
                                              float2* __restrict__ us,
                                              float* __restrict__ tav, int N) {
    int node = (blockIdx.x * 256 + threadIdx.x) >> 6;
    if (node >= N) return;
    int lane = threadIdx.x & 63;
    int sub = lane >> 4;
    int q = lane & 15;
    int s0 = rowPtr[node], s1 = rowPtr[node + 1];
    float4 a0 = make_float4(0.f, 0.f, 0.f, 0.f);
    int i = s0 + sub;
    if (i + 12 < s1) {
        int cA = srcs[i], cB = srcs[i + 4], cC = srcs[i + 8], cD = srcs[i + 12];
        i += 16;
        for (; i + 12 < s1; i += 16) {
            int nA = srcs[i], nB = srcs[i + 4], nC = srcs[i + 8], nD = srcs[i + 12];
            float2 vA = xs[(size_t)cA * 16 + q];
            float2 vB = xs[(size_t)cB * 16 + q];
            float2 vC = xs[(size_t)cC * 16 + q];
            float2 vD = xs[(size_t)cD * 16 + q];
            accq(a0, vA, vB, vC, vD);
            cA = nA; cB = nB; cC = nC; cD = nD;
        }
        float2 vA = xs[(size_t)cA * 16 + q];
        float2 vB = xs[(size_t)cB * 16 + q];
        float2 vC = xs[(size_t)cC * 16 + q];
        float2 vD = xs[(size_t)cD * 16 + q];
        accq(a0, vA, vB, vC, vD);
    }
    for (; i + 4 < s1; i += 8) {
        int sA = srcs[i];
        int sB = srcs[i + 4];
        float2 vA = xs[(size_t)sA * 16 + q];
        float2 vB = xs[(size_t)sB * 16 + q];
        accd(a0, vA, vB);
    }
    if (i < s1) {
        float2 vA = xs[(size_t)srcs[i] * 16 + q];
        acch4(a0, vA);
    }
    #pragma unroll
    for (int m = 16; m < 64; m <<= 1) {
        a0.x += __shfl_xor(a0.x, m, 64);
        a0.y += __shfl_xor(a0.y, m, 64);
        a0.z += __shfl_xor(a0.z, m, 64);
        a0.w += __shfl_xor(a0.w, m, 64);
    }
    if (sub == 0) {
        float di = dinv[node];
        float4 r = make_float4(a0.x * di, a0.y * di, a0.z * di, a0.w * di);
        u[(size_t)node * 16 + q] = r;
        us[(size_t)node * 16 + q] =
            pack_half4(r.x * di, r.y * di, r.z * di, r.w * di);
        float4 w = ((const float4*)Wattn)[q];
        float p = r.x * w.x + r.y * w.y + r.z * w.z + r.w * w.w;
        #pragma unroll
        for (int m = 1; m < 16; m <<= 1) p += __shfl_xor(p, m, 64);
        if (lane == 0) tav[node] = p;
    }
}

// ----------------------------- fused spmm2 + tail --------------------------

#define TL_PAD 68
#define BS_HPAD 136

__global__ __launch_bounds__(256) void tail_k(const float2* __restrict__ u1s,
                                              const int* __restrict__ srcs,
                                              const int* __restrict__ rowPtr,
                                              const float* __restrict__ dinv,
                                              const float* __restrict__ hg,
                                              const float* __restrict__ u1g,
                                              const float* __restrict__ resg,
                                              const float* __restrict__ thv,
                                              const float* __restrict__ tav,
                                              const float* __restrict__ Wattn,
                                              const float* __restrict__ battn,
                                              const unsigned int* __restrict__ Wf1h,
                                              const float* __restrict__ bf1,
                                              const float* __restrict__ Wf2,
                                              const float* __restrict__ bf2,
                                              const unsigned int* __restrict__ W3h,
                                              const float* __restrict__ b3,
                                              const float* __restrict__ W4,
                                              const float* __restrict__ b4,
                                              float2* __restrict__ out, int N) {
    __shared__ float lds[4 * TL_PAD];
    __shared__ _Float16 bsl[4 * BS_HPAD];
    int w = threadIdx.x >> 6;
    int lane = threadIdx.x & 63;
    int node = blockIdx.x * 4 + w;
    if (node >= N) return;
    int sub = lane >> 4, q = lane & 15;
    // hoisted independent loads: in flight during the gather below
    float hj = hg[(size_t)node * 64 + lane];
    float u1j = u1g[(size_t)node * 64 + lane];
    float resj = resg[(size_t)node * 64 + lane];
    float th = thv[node], ta = tav[node], ba = battn[0];
    float waj = Wattn[lane];
    float dinv_n = dinv[node];
    {
        int s0 = rowPtr[node], s1 = rowPtr[node + 1];
        float4 a0 = make_float4(0.f, 0.f, 0.f, 0.f);
        int i = s0 + sub;
        if (i + 12 < s1) {
            int cA = srcs[i], cB = srcs[i + 4], cC = srcs[i + 8], cD = srcs[i + 12];
            i += 16;
            for (; i + 12 < s1; i += 16) {
                int nA = srcs[i], nB = srcs[i + 4], nC = srcs[i + 8], nD = srcs[i + 12];
                float2 vA = u1s[(size_t)cA * 16 + q];
                float2 vB = u1s[(size_t)cB * 16 + q];
                float2 vC = u1s[(size_t)cC * 16 + q];
                float2 vD = u1s[(size_t)cD * 16 + q];
                accq(a0, vA, vB, vC, vD);
                cA = nA; cB = nB; cC = nC; cD = nD;
            }
            float2 vA = u1s[(size_t)cA * 16 + q];
            float2 vB = u1s[(size_t)cB * 16 + q];
            float2 vC = u1s[(size_t)cC * 16 + q];
            float2 vD = u1s[(size_t)cD * 16 + q];
            accq(a0, vA, vB, vC, vD);
        }
        for (; i + 4 < s1; i += 8) {
            int sA = srcs[i];
            int sB = srcs[i + 4];
            float2 vA = u1s[(size_t)sA * 16 + q];
            float2 vB = u1s[(size_t)sB * 16 + q];
            accd(a0, vA, vB);
        }
        if (i < s1) {
            float2 vA = u1s[(size_t)srcs[i] * 16 + q];
            acch4(a0, vA);
        }
        #pragma unroll
        for (int m = 16; m < 64; m <<= 1) {
            a0.x += __shfl_xor(a0.x, m, 64);
            a0.y += __shfl_xor(a0.y, m, 64);
            a0.z += __shfl_xor(a0.z, m, 64);
            a0.w += __shfl_xor(a0.w, m, 64);
        }
        if (sub == 0) {
            *(float4*)&lds[w * TL_PAD + q * 4] =
                make_float4(a0.x * dinv_n, a0.y * dinv_n,
                            a0.z * dinv_n, a0.w * dinv_n);
        }
    }
    // wave-private LDS: same wave wrote it; DS ops in-order per wave.
    float u2j = lds[w * TL_PAD + lane];                  // feature j = lane
    float tb = u2j * waj;
    #pragma unroll
    for (int m = 1; m < 64; m <<= 1) tb += __shfl_xor(tb, m, 64);
    float s0 = 0.75f * th + 1.5f * ta + 0.75f * tb + ba;
    float s1 = 1.5f * th - 1.5f * tb + ba;
    float s2 = 0.75f * th - 1.5f * ta + 0.75f * tb + ba;
    float mx = fmaxf(s0, fmaxf(s1, s2));
    float e0 = expf(s0 - mx), e1 = expf(s1 - mx), e2 = expf(s2 - mx);
    float inv = 1.f / (e0 + e1 + e2);
    float w0 = e0 * inv, w1 = e1 * inv, w2 = e2 * inv;
    float ca = 0.75f * w0 + 1.5f * w1 + 0.75f * w2;
    float cb = 1.5f * (w0 - w2);
    float cc = 0.75f * w0 - 1.5f * w1 + 0.75f * w2;
    float afj = ca * hj + cb * u1j + cc * u2j;
    _Float16* bsh = &bsl[w * BS_HPAD];
    bsh[lane] = (_Float16)afj;
    bsh[64 + lane] = (_Float16)hj;
    float t0 = bf1[lane], t1 = 0.f, t2 = 0.f, t3 = 0.f;
    #pragma unroll 1
    for (int kk = 0; kk < 64; kk += 4) {
        uint4 br = *(const uint4*)&bsh[2 * kk];
        unsigned int w0_ = Wf1h[(kk + 0) * 64 + lane];
        unsigned int w1_ = Wf1h[(kk + 1) * 64 + lane];
        unsigned int w2_ = Wf1h[(kk + 2) * 64 + lane];
        unsigned int w3_ = Wf1h[(kk + 3) * 64 + lane];
        t0 = __builtin_amdgcn_fdot2(as_h2(br.x), as_h2(w0_), t0, false);
        t1 = __builtin_amdgcn_fdot2(as_h2(br.y), as_h2(w1_), t1, false);
        t2 = __builtin_amdgcn_fdot2(as_h2(br.z), as_h2(w2_), t2, false);
        t3 = __builtin_amdgcn_fdot2(as_h2(br.w), as_h2(w3_), t3, false);
    }
    float t = fmaxf((t0 + t1) + (t2 + t3), 0.f);
    float fwacc = t * Wf2[lane];
    #pragma unroll
    for (int m = 1; m < 64; m <<= 1) fwacc += __shfl_xor(fwacc, m, 64);
    float fw = 1.f / (1.f + expf(-(fwacc + bf2[0])));
    float fj = 0.1f * fw * afj + (1.f - fw) * hj + 0.8f * resj;
    bsh[lane] = (_Float16)fj;
    float g0 = b3[lane], g1 = 0.f, g2 = 0.f, g3 = 0.f;
    #pragma unroll 1
    for (int kk = 0; kk < 32; kk += 4) {
        uint4 br = *(const uint4*)&bsh[2 * kk];
        unsigned int w0_ = W3h[(kk + 0) * 64 + lane];
        unsigned int w1_ = W3h[(kk + 1) * 64 + lane];
        unsigned int w2_ = W3h[(kk + 2) * 64 + lane];
        unsigned int w3_ = W3h[(kk + 3) * 64 + lane];
        g0 = __builtin_amdgcn_fdot2(as_h2(br.x), as_h2(w0_), g0, false);
        g1 = __builtin_amdgcn_fdot2(as_h2(br.y), as_h2(w1_), g1, false);
        g2 = __builtin_amdgcn_fdot2(as_h2(br.z), as_h2(w2_), g2, false);
        g3 = __builtin_amdgcn_fdot2(as_h2(br.w), as_h2(w3_), g3, false);
    }
    float g = fmaxf((g0 + g1) + (g2 + g3), 0.f);
    float2 w4 = ((const float2*)W4)[lane];
    float l0 = g * w4.x, l1 = g * w4.y;
    #pragma unroll
    for (int m = 1; m < 64; m <<= 1) {
        l0 += __shfl_xor(l0, m, 64);
        l1 += __shfl_xor(l1, m, 64);
    }
    if (lane == 0) out[node] = make_float2(l0 + b4[0], l1 + b4[1]);
}

// ----------------------------- launch --------------------------------------

extern "C" void kernel_launch(void* const* d_in, const int* in_sizes, int n_in,
                              void* d_out, int out_size, void* d_ws, size_t ws_size,
                              hipStream_t stream) {
    const float* in_feat = (const float*)d_in[0];
    const int*   src     = (const int*)d_in[1];
    const int*   dst     = (const int*)d_in[2];
    const float* W1   = (const float*)d_in[3];
    const float* b1   = (const float*)d_in[4];
    const float* W2   = (const float*)d_in[5];
    const float* b2   = (const float*)d_in[6];
    const float* Wres = (const float*)d_in[7];
    const float* bres = (const float*)d_in[8];
    const float* Wattn = (const float*)d_in[9];
    const float* battn = (const float*)d_in[10];
    const float* Wf1  = (const float*)d_in[11];
    const float* bf1  = (const float*)d_in[12];
    const float* Wf2  = (const float*)d_in[13];
    const float* bf2  = (const float*)d_in[14];
    const float* W3   = (const float*)d_in[15];
    const float* b3   = (const float*)d_in[16];
    const float* W4   = (const float*)d_in[17];
    const float* b4   = (const float*)d_in[18];

    const int N = in_sizes[0] / 128;
    const int E = in_sizes[1];
    const int B = (N + BNODES - 1) >> BSHIFT;

    char* p = (char*)d_ws;
    auto take = [&](size_t bytes) -> char* {
        char* r = p;
        p += (bytes + 255) & ~(size_t)255;
        return r;
    };
    int*   bucketCount  = (int*)take((size_t)(B + 1) * 4);
    int*   bucketPtr    = (int*)take((size_t)(B + 1) * 4);
    int*   bucketCursor = (int*)take((size_t)(B + 1) * 4);
    int*   rowPtr       = (int*)take((size_t)(N + 1) * 4);
    float* dinv         = (float*)take((size_t)N * 4);
    int*   srcSorted    = (int*)take((size_t)E * 4);
    int*   ebuf         = (int*)take((size_t)E * 4);   // OWN buffer: scatter
                                                       // runs concurrent with
                                                       // dense2res (reads h1)
    float* thv          = (float*)take((size_t)N * 4);
    float* tav          = (float*)take((size_t)N * 4);
    unsigned int* Wf1h  = (unsigned int*)take((size_t)64 * 64 * 4);
    unsigned int* W3h   = (unsigned int*)take((size_t)32 * 64 * 4);
    float* h1  = (float*)take((size_t)N * 256);
    float* h   = (float*)take((size_t)N * 256);
    float* hs  = (float*)take((size_t)N * 128);   // f16 packed, 64 halves/row
    float* res = (float*)take((size_t)N * 256);
    float* u1  = (float*)take((size_t)N * 256);
    float* u1s = (float*)take((size_t)N * 128);   // f16 packed

    int eb = (E + CHUNK - 1) / CHUNK;
    int dqb = (N + 255) / 256;                    // 256-node dense blocks
    int spb = (N * 64 + 255) / 256;
    int tlb = (N + 3) / 4;

    hipMemsetAsync(bucketCount, 0, (size_t)B * 4, stream);

    // K1: bucket_count || dense1 || pack_w
    fused1_k<<<eb + dqb + 24, 256, 0, stream>>>(dst, bucketCount, E, B,
                                                in_feat, W1, b1, h1, N,
                                                Wf1, W3, Wf1h, W3h, eb, dqb);
    // K2: scan
    bucket_scan_k<<<1, 64, 0, stream>>>(bucketCount, bucketPtr, bucketCursor,
                                        rowPtr, B, N, E);
    // K3: scatter || dense2res
    fused3_k<<<eb + dqb, 256, 0, stream>>>(src, dst, bucketCursor, ebuf, E, B,
                                           h1, W2, b2, Wres, bres, Wattn, dinv,
                                           h, (float2*)hs, res, thv, N, eb, dqb);

    csr_build_k<<<B, 256, 0, stream>>>(ebuf, bucketPtr, rowPtr, dinv, srcSorted, N);

    spmm_k<<<spb, 256, 0, stream>>>((const float2*)hs, srcSorted, rowPtr, dinv,
                                    Wattn, (float4*)u1, (float2*)u1s, tav, N);

    tail_k<<<tlb, 256, 0, stream>>>((const float2*)u1s, srcSorted, rowPtr, dinv,
                                    h, u1, res, thv, tav, Wattn, battn,
                                    Wf1h, bf1, Wf2, bf2, W3h, b3, W4, b4,
                                    (float2*)d_out, N);
}

// Round 12
// 329.669 us; speedup vs baseline: 1.1216x; 1.0446x over previous
//
#include <hip/hip_runtime.h>
#include <hip/hip_fp16.h>
#include <math.h>

// ---------------------------------------------------------------------------
// ADCGNN amazon: N=50000, E=1.6M, IN=128, H=64, C=2, K=3
//
// R12: fp16 dot2 GEMVs (24KB weights fit L1): tail 122->89. [367]
// R13: pk-tree accumulate: flat -> ~45us gather latency floor.
// R14: src-index rotation: tail 89.5->84. [362]
// R15: grid-concat fusion (count||dense1, scatter||dense2res). [344 best]
// R16 (this round): u1s as fp8 e4m3 rows (64B = 1 line/edge, table 3.2MB
//     FITS per-XCD 4MB L2 -> gather becomes L2-hit latency class). x8
//     pre-scale lifts values out of e4m3 subnormal range; decode x0.125
//     folded into dinv_n (exact, linear). hs stays fp16 (limits error to
//     the u2 path). fp32 accumulate.
//
// Pipeline:
//   K1: bucket_count || dense1 || pack_w
//   K2: bucket_scan
//   K3: bucket_scatter || dense2res
//   csr_build
//   spmm1 (rotated gather, fp16 src; writes u fp32, u1s fp8, ta)
//   tail  (rotated fp8 gather + softmax + dot2 GEMVs)
// ---------------------------------------------------------------------------

#define BSHIFT 7
#define BNODES 128
#define BMAX   512
#define EPT    32
#define CHUNK  (256 * EPT)
#define CAP    8192
#define F8SCALE 8.0f
#define F8INV  0.125f

typedef _Float16 h2v __attribute__((ext_vector_type(2)));
typedef float f2v __attribute__((ext_vector_type(2)));

__device__ __forceinline__ h2v as_h2(unsigned int u) {
    union { unsigned int u; h2v h; } c; c.u = u; return c.h;
}

__device__ __forceinline__ void fma4(float4& acc, float s, const float4 w) {
    acc.x += s * w.x; acc.y += s * w.y; acc.z += s * w.z; acc.w += s * w.w;
}

__device__ __forceinline__ float2 pack_half4(float x, float y, float z, float w) {
    union { __half2 h[2]; float2 f; } u;
    u.h[0] = __floats2half2_rn(x, y);
    u.h[1] = __floats2half2_rn(z, w);
    return u.f;
}

__device__ __forceinline__ void acch4(float4& a, float2 p) {
    union { float2 f; __half2 h[2]; } u; u.f = p;
    float2 lo = __half22float2(u.h[0]);
    float2 hi = __half22float2(u.h[1]);
    a.x += lo.x; a.y += lo.y; a.z += hi.x; a.w += hi.y;
}

// depth-2 fp16 pairwise tree over 4 edges, then fp32 accumulate.
__device__ __forceinline__ void accq(float4& a, float2 pA, float2 pB,
                                     float2 pC, float2 pD) {
    union { float2 f; __half2 h[2]; } A, B, C, D;
    A.f = pA; B.f = pB; C.f = pC; D.f = pD;
    __half2 s0 = __hadd2(__hadd2(A.h[0], B.h[0]), __hadd2(C.h[0], D.h[0]));
    __half2 s1 = __hadd2(__hadd2(A.h[1], B.h[1]), __hadd2(C.h[1], D.h[1]));
    float2 lo = __half22float2(s0), hi = __half22float2(s1);
    a.x += lo.x; a.y += lo.y; a.z += hi.x; a.w += hi.y;
}

__device__ __forceinline__ void accd(float4& a, float2 pA, float2 pB) {
    union { float2 f; __half2 h[2]; } A, B;
    A.f = pA; B.f = pB;
    __half2 s0 = __hadd2(A.h[0], B.h[0]);
    __half2 s1 = __hadd2(A.h[1], B.h[1]);
    float2 lo = __half22float2(s0), hi = __half22float2(s1);
    a.x += lo.x; a.y += lo.y; a.z += hi.x; a.w += hi.y;
}

// fp8 (e4m3) unpack-accumulate: 4 fp8 in a uint -> fp32 accumulate.
__device__ __forceinline__ void accf8(float4& a, unsigned int v) {
    f2v lo = __builtin_amdgcn_cvt_pk_f32_fp8(v, false);
    f2v hi = __builtin_amdgcn_cvt_pk_f32_fp8(v, true);
    a.x += lo[0]; a.y += lo[1]; a.z += hi[0]; a.w += hi[1];
}

// ----------------------------- K1: count || dense1 || pack_w ---------------

__global__ __launch_bounds__(256) void fused1_k(const int* __restrict__ dst,
                                                int* __restrict__ bucketCount,
                                                int E, int B,
                                                const float* __restrict__ Xg,
                                                const float* __restrict__ W1,
                                                const float* __restrict__ b1,
                                                float* __restrict__ h1, int N,
                                                const float* __restrict__ Wf1,
                                                const float* __restrict__ W3,
                                                unsigned int* __restrict__ Wf1h,
                                                unsigned int* __restrict__ W3h,
                                                int eb, int d1b) {
    __shared__ float smem[256 * 36];
    int bid = blockIdx.x;
    if (bid < eb) {
        int* cnt = (int*)smem;
        for (int i = threadIdx.x; i < B; i += 256) cnt[i] = 0;
        __syncthreads();
        int base = bid * CHUNK;
        #pragma unroll
        for (int t = 0; t < EPT; t++) {
            int e = base + t * 256 + threadIdx.x;
            if (e < E) atomicAdd(&cnt[dst[e] >> BSHIFT], 1);
        }
        __syncthreads();
        for (int i = threadIdx.x; i < B; i += 256)
            if (cnt[i] > 0) atomicAdd(&bucketCount[i], cnt[i]);
        return;
    }
    bid -= eb;
    if (bid < d1b) {
        int n0 = bid * 256;
        int n = n0 + threadIdx.x;
        bool act = (n < N);
        const float4* W = (const float4*)W1;
        const float4* Bb = (const float4*)b1;
        float4 acc[16];
        #pragma unroll
        for (int j = 0; j < 16; j++) acc[j] = Bb[j];
        if (act) {
            const float4* X = (const float4*)Xg + (size_t)n * 32;
            float4 a = X[0];
            #pragma unroll 1
            for (int kc = 0; kc < 32; kc++) {
                float4 an = a;
                if (kc + 1 < 32) an = X[kc + 1];
                const float4* wrow = W + kc * 64;
                #pragma unroll
                for (int j = 0; j < 16; j++) {
                    fma4(acc[j], a.x, wrow[j]);
                    fma4(acc[j], a.y, wrow[16 + j]);
                    fma4(acc[j], a.z, wrow[32 + j]);
                    fma4(acc[j], a.w, wrow[48 + j]);
                }
                a = an;
            }
        }
        #pragma unroll
        for (int j = 0; j < 16; j++) {
            float4 v = acc[j];
            acc[j] = make_float4(fmaxf(v.x, 0.f), fmaxf(v.y, 0.f),
                                 fmaxf(v.z, 0.f), fmaxf(v.w, 0.f));
        }
        float4* o4 = (float4*)h1;
        #pragma unroll
        for (int r2 = 0; r2 < 2; r2++) {
            __syncthreads();
            float* myrow = &smem[threadIdx.x * 36];
            #pragma unroll
            for (int j = 0; j < 8; j++) *(float4*)&myrow[4 * j] = acc[r2 * 8 + j];
            __syncthreads();
            #pragma unroll
            for (int r = 0; r < 8; r++) {
                int idx = r * 256 + threadIdx.x;
                int row = idx >> 3, col = idx & 7;
                int gn = n0 + row;
                if (gn < N)
                    o4[(size_t)gn * 16 + r2 * 8 + col] =
                        *(float4*)&smem[row * 36 + col * 4];
            }
        }
        return;
    }
    bid -= d1b;
    int t = bid * 256 + threadIdx.x;
    if (t < 64 * 64) {
        int kk = t >> 6, j = t & 63;
        union { __half2 h; unsigned int u; } c;
        c.h = __floats2half2_rn(Wf1[(2 * kk) * 64 + j], Wf1[(2 * kk + 1) * 64 + j]);
        Wf1h[t] = c.u;
    } else if (t < 64 * 64 + 32 * 64) {
        int r = t - 64 * 64;
        int kk = r >> 6, j = r & 63;
        union { __half2 h; unsigned int u; } c;
        c.h = __floats2half2_rn(W3[(2 * kk) * 64 + j], W3[(2 * kk + 1) * 64 + j]);
        W3h[r] = c.u;
    }
}

// ----------------------------- K2: bucket_scan ------------------------------

__global__ __launch_bounds__(64) void bucket_scan_k(const int* __restrict__ bucketCount,
                                                    int* __restrict__ bucketPtr,
                                                    int* __restrict__ bucketCursor,
                                                    int* __restrict__ rowPtr,
                                                    int B, int N, int E) {
    int lane = threadIdx.x;
    const int PT = (BMAX + 63) / 64;
    int v[PT]; int s = 0;
    #pragma unroll
    for (int t = 0; t < PT; t++) {
        int i = lane * PT + t;
        v[t] = (i < B) ? bucketCount[i] : 0;
        s += v[t];
    }
    int x = s;
    #pragma unroll
    for (int off = 1; off < 64; off <<= 1) {
        int y = __shfl_up(x, off, 64);
        if (lane >= off) x += y;
    }
    int run = x - s;
    #pragma unroll
    for (int t = 0; t < PT; t++) {
        int i = lane * PT + t;
        if (i < B) { bucketPtr[i] = run; bucketCursor[i] = run; }
        run += v[t];
    }
    if (lane == 63) bucketPtr[B] = x;
    if (lane == 0) rowPtr[N] = E;
}

// ----------------------------- K3: scatter || dense2res ---------------------

__global__ __launch_bounds__(256) void fused3_k(const int* __restrict__ src,
                                                const int* __restrict__ dst,
                                                int* __restrict__ bucketCursor,
                                                int* __restrict__ ebuf,
                                                int E, int B,
                                                const float* __restrict__ h1,
                                                const float* __restrict__ W2,
                                                const float* __restrict__ b2,
                                                const float* __restrict__ Wres,
                                                const float* __restrict__ bres,
                                                const float* __restrict__ Wattn,
                                                const float* __restrict__ dinv,
                                                float* __restrict__ hg,
                                                float2* __restrict__ hs2,
                                                float* __restrict__ resg,
                                                float* __restrict__ thv, int N,
                                                int eb, int d2b) {
    __shared__ float smem[256 * 36];
    int bid = blockIdx.x;
    if (bid < eb) {
        int* cnt = (int*)smem;
        int* base = cnt + BMAX;
        int* cur = base + BMAX;
        for (int i = threadIdx.x; i < B; i += 256) { cnt[i] = 0; cur[i] = 0; }
        __syncthreads();
        int cbase = bid * CHUNK;
        int d[EPT];
        #pragma unroll
        for (int t = 0; t < EPT; t++) {
            int e = cbase + t * 256 + threadIdx.x;
            d[t] = (e < E) ? dst[e] : -1;
            if (d[t] >= 0) atomicAdd(&cnt[d[t] >> BSHIFT], 1);
        }
        __syncthreads();
        for (int i = threadIdx.x; i < B; i += 256)
            if (cnt[i] > 0) base[i] = atomicAdd(&bucketCursor[i], cnt[i]);
        __syncthreads();
        #pragma unroll
        for (int t = 0; t < EPT; t++) {
            int e = cbase + t * 256 + threadIdx.x;
            if (d[t] >= 0) {
                int b = d[t] >> BSHIFT;
                int c = atomicAdd(&cur[b], 1);
                int pack = (src[e] & 0xFFFF) | ((d[t] & (BNODES - 1)) << 16);
                ebuf[base[b] + c] = pack;
            }
        }
        return;
    }
    bid -= eb;
    int n0 = bid * 256;
    int n = n0 + threadIdx.x;
    bool act = (n < N);
    const float4* W = (const float4*)W2;
    const float4* Bb = (const float4*)b2;
    float4 acc[16];
    #pragma unroll
    for (int j = 0; j < 16; j++) acc[j] = Bb[j];
    if (act) {
        const float4* X = (const float4*)h1 + (size_t)n * 16;
        float4 a = X[0];
        #pragma unroll 1
        for (int kc = 0; kc < 16; kc++) {
            float4 an = a;
            if (kc + 1 < 16) an = X[kc + 1];
            const float4* wrow = W + kc * 64;
            #pragma unroll
            for (int j = 0; j < 16; j++) {
                fma4(acc[j], a.x, wrow[j]);
                fma4(acc[j], a.y, wrow[16 + j]);
                fma4(acc[j], a.z, wrow[32 + j]);
                fma4(acc[j], a.w, wrow[48 + j]);
            }
            a = an;
        }
    }
    const float4* Wa = (const float4*)Wattn;
    float th = 0.f;
    #pragma unroll
    for (int j = 0; j < 16; j++) {
        float4 v = acc[j];
        v.x = fmaxf(v.x, 0.f); v.y = fmaxf(v.y, 0.f);
        v.z = fmaxf(v.z, 0.f); v.w = fmaxf(v.w, 0.f);
        acc[j] = v;
        float4 w = Wa[j];
        th += v.x * w.x + v.y * w.y + v.z * w.z + v.w * w.w;
    }
    if (act) thv[n] = th;
    float4* h4 = (float4*)hg;
    #pragma unroll
    for (int r2 = 0; r2 < 2; r2++) {
        __syncthreads();
        float* myrow = &smem[threadIdx.x * 36];
        #pragma unroll
        for (int j = 0; j < 8; j++) *(float4*)&myrow[4 * j] = acc[r2 * 8 + j];
        __syncthreads();
        #pragma unroll
        for (int r = 0; r < 8; r++) {
            int idx = r * 256 + threadIdx.x;
            int row = idx >> 3, col = idx & 7;
            int gn = n0 + row;
            if (gn < N) {
                float4 v = *(float4*)&smem[row * 36 + col * 4];
                h4[(size_t)gn * 16 + r2 * 8 + col] = v;
                float di = dinv[gn];
                hs2[(size_t)gn * 16 + r2 * 8 + col] =
                    pack_half4(v.x * di, v.y * di, v.z * di, v.w * di);
            }
        }
    }
    const float4* WR = (const float4*)Wres;
    const float4* BR = (const float4*)bres;
    float4 acc2[16];
    #pragma unroll
    for (int j = 0; j < 16; j++) acc2[j] = BR[j];
    #pragma unroll 1
    for (int kc = 0; kc < 16; kc++) {
        float4 a2 = acc[kc];
        const float4* wrow = WR + kc * 64;
        #pragma unroll
        for (int j = 0; j < 16; j++) {
            fma4(acc2[j], a2.x, wrow[j]);
            fma4(acc2[j], a2.y, wrow[16 + j]);
            fma4(acc2[j], a2.z, wrow[32 + j]);
            fma4(acc2[j], a2.w, wrow[48 + j]);
        }
    }
    float4* r4 = (float4*)resg;
    #pragma unroll
    for (int r2 = 0; r2 < 2; r2++) {
        __syncthreads();
        float* myrow = &smem[threadIdx.x * 36];
        #pragma unroll
        for (int j = 0; j < 8; j++) *(float4*)&myrow[4 * j] = acc2[r2 * 8 + j];
        __syncthreads();
        #pragma unroll
        for (int r = 0; r < 8; r++) {
            int idx = r * 256 + threadIdx.x;
            int row = idx >> 3, col = idx & 7;
            int gn = n0 + row;
            if (gn < N)
                r4[(size_t)gn * 16 + r2 * 8 + col] =
                    *(float4*)&smem[row * 36 + col * 4];
        }
    }
}

// ----------------------------- csr_build ------------------------------------

__global__ __launch_bounds__(256) void csr_build_k(const int* __restrict__ ebuf,
                                                   const int* __restrict__ bucketPtr,
                                                   int* __restrict__ rowPtr,
                                                   float* __restrict__ dinv,
                                                   int* __restrict__ srcSorted,
                                                   int N) {
    __shared__ int deg[BNODES];
    __shared__ int rp[BNODES + 1];
    __shared__ int cur[BNODES];
    __shared__ int stage[CAP];
    int b = blockIdx.x;
    int nodeBase = b << BSHIFT;
    int nNodes = min(BNODES, N - nodeBase);
    int eBase = bucketPtr[b];
    int eCnt = bucketPtr[b + 1] - eBase;
    for (int i = threadIdx.x; i < BNODES; i += 256) deg[i] = 0;
    __syncthreads();
    for (int i = threadIdx.x; i < eCnt; i += 256)
        atomicAdd(&deg[(ebuf[eBase + i] >> 16) & (BNODES - 1)], 1);
    __syncthreads();
    if (threadIdx.x < 64) {
        int lane = threadIdx.x;
        int d0 = deg[2 * lane], d1 = deg[2 * lane + 1];
        int s = d0 + d1;
        int x = s;
        #pragma unroll
        for (int off = 1; off < 64; off <<= 1) {
            int y = __shfl_up(x, off, 64);
            if (lane >= off) x += y;
        }
        int ex = x - s;
        rp[2 * lane] = ex;
        rp[2 * lane + 1] = ex + d0;
        cur[2 * lane] = ex;
        cur[2 * lane + 1] = ex + d0;
        if (lane == 63) rp[BNODES] = x;
    }
    __syncthreads();
    for (int j = threadIdx.x; j < nNodes; j += 256) {
        rowPtr[nodeBase + j] = eBase + rp[j];
        int dg = deg[j];
        dinv[nodeBase + j] = rsqrtf((float)(dg > 1 ? dg : 1));
    }
    if (eCnt <= CAP) {
        for (int i = threadIdx.x; i < eCnt; i += 256) {
            int p = ebuf[eBase + i];
            int ld = (p >> 16) & (BNODES - 1);
            int pos = atomicAdd(&cur[ld], 1);
            stage[pos] = p & 0xFFFF;
        }
        __syncthreads();
        for (int i = threadIdx.x; i < eCnt; i += 256)
            srcSorted[eBase + i] = stage[i];
    } else {
        for (int i = threadIdx.x; i < eCnt; i += 256) {
            int p = ebuf[eBase + i];
            int ld = (p >> 16) & (BNODES - 1);
            int pos = atomicAdd(&cur[ld], 1);
            srcSorted[eBase + pos] = p & 0xFFFF;
        }
    }
}

// ----------------------------- SPMM (spmm1) --------------------------------
// Wave per node (4/block). Rotated-index fp16 gather; writes u (fp32),
// u1s (fp8 e4m3, x8 scale), ta.

__global__ __launch_bounds__(256) void spmm_k(const float2* __restrict__ xs,
                                              const int* __restrict__ srcs,
                                              const int* __restrict__ rowPtr,
                                              const float* __restrict__ dinv,
                                              const float* __restrict__ Wattn,
                                              float4* __restrict__ u,
                                              unsigned int* __restrict__ us,
                                              float* __restrict__ tav, int N) {
    int node = (blockIdx.x * 256 + threadIdx.x) >> 6;
    if (node >= N) return;
    int lane = threadIdx.x & 63;
    int sub = lane >> 4;
    int q = lane & 15;
    int s0 = rowPtr[node], s1 = rowPtr[node + 1];
    float4 a0 = make_float4(0.f, 0.f, 0.f, 0.f);
    int i = s0 + sub;
    if (i + 12 < s1) {
        int cA = srcs[i], cB = srcs[i + 4], cC = srcs[i + 8], cD = srcs[i + 12];
        i += 16;
        for (; i + 12 < s1; i += 16) {
            int nA = srcs[i], nB = srcs[i + 4], nC = srcs[i + 8], nD = srcs[i + 12];
            float2 vA = xs[(size_t)cA * 16 + q];
            float2 vB = xs[(size_t)cB * 16 + q];
            float2 vC = xs[(size_t)cC * 16 + q];
            float2 vD = xs[(size_t)cD * 16 + q];
            accq(a0, vA, vB, vC, vD);
            cA = nA; cB = nB; cC = nC; cD = nD;
        }
        float2 vA = xs[(size_t)cA * 16 + q];
        float2 vB = xs[(size_t)cB * 16 + q];
        float2 vC = xs[(size_t)cC * 16 + q];
        float2 vD = xs[(size_t)cD * 16 + q];
        accq(a0, vA, vB, vC, vD);
    }
    for (; i + 4 < s1; i += 8) {
        int sA = srcs[i];
        int sB = srcs[i + 4];
        float2 vA = xs[(size_t)sA * 16 + q];
        float2 vB = xs[(size_t)sB * 16 + q];
        accd(a0, vA, vB);
    }
    if (i < s1) {
        float2 vA = xs[(size_t)srcs[i] * 16 + q];
        acch4(a0, vA);
    }
    #pragma unroll
    for (int m = 16; m < 64; m <<= 1) {
        a0.x += __shfl_xor(a0.x, m, 64);
        a0.y += __shfl_xor(a0.y, m, 64);
        a0.z += __shfl_xor(a0.z, m, 64);
        a0.w += __shfl_xor(a0.w, m, 64);
    }
    if (sub == 0) {
        float di = dinv[node];
        float4 r = make_float4(a0.x * di, a0.y * di, a0.z * di, a0.w * di);
        u[(size_t)node * 16 + q] = r;
        // fp8 pack with x8 scale (decode folds x0.125 into dinv_n)
        float sc = di * F8SCALE;
        unsigned int pk = 0;
        pk = __builtin_amdgcn_cvt_pk_fp8_f32(r.x * sc, r.y * sc, pk, false);
        pk = __builtin_amdgcn_cvt_pk_fp8_f32(r.z * sc, r.w * sc, pk, true);
        us[(size_t)node * 16 + q] = pk;
        float4 w = ((const float4*)Wattn)[q];
        float p = r.x * w.x + r.y * w.y + r.z * w.z + r.w * w.w;
        #pragma unroll
        for (int m = 1; m < 16; m <<= 1) p += __shfl_xor(p, m, 64);
        if (lane == 0) tav[node] = p;
    }
}

// ----------------------------- fused spmm2 + tail --------------------------
// Wave per node (4/block). fp8 gather (1 line/edge, 3.2MB table L2-resident);
// rotated indices; hoisted node-row loads; dot2 GEMVs.

#define TL_PAD 68
#define BS_HPAD 136

__global__ __launch_bounds__(256) void tail_k(const unsigned int* __restrict__ u1s,
                                              const int* __restrict__ srcs,
                                              const int* __restrict__ rowPtr,
                                              const float* __restrict__ dinv,
                                              const float* __restrict__ hg,
                                              const float* __restrict__ u1g,
                                              const float* __restrict__ resg,
                                              const float* __restrict__ thv,
                                              const float* __restrict__ tav,
                                              const float* __restrict__ Wattn,
                                              const float* __restrict__ battn,
                                              const unsigned int* __restrict__ Wf1h,
                                              const float* __restrict__ bf1,
                                              const float* __restrict__ Wf2,
                                              const float* __restrict__ bf2,
                                              const unsigned int* __restrict__ W3h,
                                              const float* __restrict__ b3,
                                              const float* __restrict__ W4,
                                              const float* __restrict__ b4,
                                              float2* __restrict__ out, int N) {
    __shared__ float lds[4 * TL_PAD];
    __shared__ _Float16 bsl[4 * BS_HPAD];
    int w = threadIdx.x >> 6;
    int lane = threadIdx.x & 63;
    int node = blockIdx.x * 4 + w;
    if (node >= N) return;
    int sub = lane >> 4, q = lane & 15;
    // hoisted independent loads: in flight during the gather below
    float hj = hg[(size_t)node * 64 + lane];
    float u1j = u1g[(size_t)node * 64 + lane];
    float resj = resg[(size_t)node * 64 + lane];
    float th = thv[node], ta = tav[node], ba = battn[0];
    float waj = Wattn[lane];
    float dinv_n = dinv[node] * F8INV;    // undo x8 fp8 pre-scale (linear)
    {
        int s0 = rowPtr[node], s1 = rowPtr[node + 1];
        float4 a0 = make_float4(0.f, 0.f, 0.f, 0.f);
        float4 a1 = a0;
        int i = s0 + sub;
        if (i + 12 < s1) {
            int cA = srcs[i], cB = srcs[i + 4], cC = srcs[i + 8], cD = srcs[i + 12];
            i += 16;
            for (; i + 12 < s1; i += 16) {
                int nA = srcs[i], nB = srcs[i + 4], nC = srcs[i + 8], nD = srcs[i + 12];
                unsigned int vA = u1s[(size_t)cA * 16 + q];
                unsigned int vB = u1s[(size_t)cB * 16 + q];
                unsigned int vC = u1s[(size_t)cC * 16 + q];
                unsigned int vD = u1s[(size_t)cD * 16 + q];
                accf8(a0, vA); accf8(a1, vB); accf8(a0, vC); accf8(a1, vD);
                cA = nA; cB = nB; cC = nC; cD = nD;
            }
            unsigned int vA = u1s[(size_t)cA * 16 + q];
            unsigned int vB = u1s[(size_t)cB * 16 + q];
            unsigned int vC = u1s[(size_t)cC * 16 + q];
            unsigned int vD = u1s[(size_t)cD * 16 + q];
            accf8(a0, vA); accf8(a1, vB); accf8(a0, vC); accf8(a1, vD);
        }
        for (; i + 4 < s1; i += 8) {
            unsigned int vA = u1s[(size_t)srcs[i] * 16 + q];
            unsigned int vB = u1s[(size_t)srcs[i + 4] * 16 + q];
            accf8(a0, vA); accf8(a1, vB);
        }
        if (i < s1) {
            unsigned int vA = u1s[(size_t)srcs[i] * 16 + q];
            accf8(a0, vA);
        }
        a0.x += a1.x; a0.y += a1.y; a0.z += a1.z; a0.w += a1.w;
        #pragma unroll
        for (int m = 16; m < 64; m <<= 1) {
            a0.x += __shfl_xor(a0.x, m, 64);
            a0.y += __shfl_xor(a0.y, m, 64);
            a0.z += __shfl_xor(a0.z, m, 64);
            a0.w += __shfl_xor(a0.w, m, 64);
        }
        if (sub == 0) {
            *(float4*)&lds[w * TL_PAD + q * 4] =
                make_float4(a0.x * dinv_n, a0.y * dinv_n,
                            a0.z * dinv_n, a0.w * dinv_n);
        }
    }
    // wave-private LDS: same wave wrote it; DS ops in-order per wave.
    float u2j = lds[w * TL_PAD + lane];                  // feature j = lane
    float tb = u2j * waj;
    #pragma unroll
    for (int m = 1; m < 64; m <<= 1) tb += __shfl_xor(tb, m, 64);
    float s0 = 0.75f * th + 1.5f * ta + 0.75f * tb + ba;
    float s1 = 1.5f * th - 1.5f * tb + ba;
    float s2 = 0.75f * th - 1.5f * ta + 0.75f * tb + ba;
    float mx = fmaxf(s0, fmaxf(s1, s2));
    float e0 = expf(s0 - mx), e1 = expf(s1 - mx), e2 = expf(s2 - mx);
    float inv = 1.f / (e0 + e1 + e2);
    float w0 = e0 * inv, w1 = e1 * inv, w2 = e2 * inv;
    float ca = 0.75f * w0 + 1.5f * w1 + 0.75f * w2;
    float cb = 1.5f * (w0 - w2);
    float cc = 0.75f * w0 - 1.5f * w1 + 0.75f * w2;
    float afj = ca * hj + cb * u1j + cc * u2j;
    _Float16* bsh = &bsl[w * BS_HPAD];
    bsh[lane] = (_Float16)afj;
    bsh[64 + lane] = (_Float16)hj;
    float t0 = bf1[lane], t1 = 0.f, t2 = 0.f, t3 = 0.f;
    #pragma unroll 1
    for (int kk = 0; kk < 64; kk += 4) {
        uint4 br = *(const uint4*)&bsh[2 * kk];
        unsigned int w0_ = Wf1h[(kk + 0) * 64 + lane];
        unsigned int w1_ = Wf1h[(kk + 1) * 64 + lane];
        unsigned int w2_ = Wf1h[(kk + 2) * 64 + lane];
        unsigned int w3_ = Wf1h[(kk + 3) * 64 + lane];
        t0 = __builtin_amdgcn_fdot2(as_h2(br.x), as_h2(w0_), t0, false);
        t1 = __builtin_amdgcn_fdot2(as_h2(br.y), as_h2(w1_), t1, false);
        t2 = __builtin_amdgcn_fdot2(as_h2(br.z), as_h2(w2_), t2, false);
        t3 = __builtin_amdgcn_fdot2(as_h2(br.w), as_h2(w3_), t3, false);
    }
    float t = fmaxf((t0 + t1) + (t2 + t3), 0.f);
    float fwacc = t * Wf2[lane];
    #pragma unroll
    for (int m = 1; m < 64; m <<= 1) fwacc += __shfl_xor(fwacc, m, 64);
    float fw = 1.f / (1.f + expf(-(fwacc + bf2[0])));
    float fj = 0.1f * fw * afj + (1.f - fw) * hj + 0.8f * resj;
    bsh[lane] = (_Float16)fj;
    float g0 = b3[lane], g1 = 0.f, g2 = 0.f, g3 = 0.f;
    #pragma unroll 1
    for (int kk = 0; kk < 32; kk += 4) {
        uint4 br = *(const uint4*)&bsh[2 * kk];
        unsigned int w0_ = W3h[(kk + 0) * 64 + lane];
        unsigned int w1_ = W3h[(kk + 1) * 64 + lane];
        unsigned int w2_ = W3h[(kk + 2) * 64 + lane];
        unsigned int w3_ = W3h[(kk + 3) * 64 + lane];
        g0 = __builtin_amdgcn_fdot2(as_h2(br.x), as_h2(w0_), g0, false);
        g1 = __builtin_amdgcn_fdot2(as_h2(br.y), as_h2(w1_), g1, false);
        g2 = __builtin_amdgcn_fdot2(as_h2(br.z), as_h2(w2_), g2, false);
        g3 = __builtin_amdgcn_fdot2(as_h2(br.w), as_h2(w3_), g3, false);
    }
    float g = fmaxf((g0 + g1) + (g2 + g3), 0.f);
    float2 w4 = ((const float2*)W4)[lane];
    float l0 = g * w4.x, l1 = g * w4.y;
    #pragma unroll
    for (int m = 1; m < 64; m <<= 1) {
        l0 += __shfl_xor(l0, m, 64);
        l1 += __shfl_xor(l1, m, 64);
    }
    if (lane == 0) out[node] = make_float2(l0 + b4[0], l1 + b4[1]);
}

// ----------------------------- launch --------------------------------------

extern "C" void kernel_launch(void* const* d_in, const int* in_sizes, int n_in,
                              void* d_out, int out_size, void* d_ws, size_t ws_size,
                              hipStream_t stream) {
    const float* in_feat = (const float*)d_in[0];
    const int*   src     = (const int*)d_in[1];
    const int*   dst     = (const int*)d_in[2];
    const float* W1   = (const float*)d_in[3];
    const float* b1   = (const float*)d_in[4];
    const float* W2   = (const float*)d_in[5];
    const float* b2   = (const float*)d_in[6];
    const float* Wres = (const float*)d_in[7];
    const float* bres = (const float*)d_in[8];
    const float* Wattn = (const float*)d_in[9];
    const float* battn = (const float*)d_in[10];
    const float* Wf1  = (const float*)d_in[11];
    const float* bf1  = (const float*)d_in[12];
    const float* Wf2  = (const float*)d_in[13];
    const float* bf2  = (const float*)d_in[14];
    const float* W3   = (const float*)d_in[15];
    const float* b3   = (const float*)d_in[16];
    const float* W4   = (const float*)d_in[17];
    const float* b4   = (const float*)d_in[18];

    const int N = in_sizes[0] / 128;
    const int E = in_sizes[1];
    const int B = (N + BNODES - 1) >> BSHIFT;

    char* p = (char*)d_ws;
    auto take = [&](size_t bytes) -> char* {
        char* r = p;
        p += (bytes + 255) & ~(size_t)255;
        return r;
    };
    int*   bucketCount  = (int*)take((size_t)(B + 1) * 4);
    int*   bucketPtr    = (int*)take((size_t)(B + 1) * 4);
    int*   bucketCursor = (int*)take((size_t)(B + 1) * 4);
    int*   rowPtr       = (int*)take((size_t)(N + 1) * 4);
    float* dinv         = (float*)take((size_t)N * 4);
    int*   srcSorted    = (int*)take((size_t)E * 4);
    int*   ebuf         = (int*)take((size_t)E * 4);
    float* thv          = (float*)take((size_t)N * 4);
    float* tav          = (float*)take((size_t)N * 4);
    unsigned int* Wf1h  = (unsigned int*)take((size_t)64 * 64 * 4);
    unsigned int* W3h   = (unsigned int*)take((size_t)32 * 64 * 4);
    float* h1  = (float*)take((size_t)N * 256);
    float* h   = (float*)take((size_t)N * 256);
    float* hs  = (float*)take((size_t)N * 128);   // f16 packed
    float* res = (float*)take((size_t)N * 256);
    float* u1  = (float*)take((size_t)N * 256);
    unsigned int* u1s = (unsigned int*)take((size_t)N * 64);  // fp8 rows (64B)

    int eb = (E + CHUNK - 1) / CHUNK;
    int dqb = (N + 255) / 256;
    int spb = (N * 64 + 255) / 256;
    int tlb = (N + 3) / 4;

    hipMemsetAsync(bucketCount, 0, (size_t)B * 4, stream);

    fused1_k<<<eb + dqb + 24, 256, 0, stream>>>(dst, bucketCount, E, B,
                                                in_feat, W1, b1, h1, N,
                                                Wf1, W3, Wf1h, W3h, eb, dqb);
    bucket_scan_k<<<1, 64, 0, stream>>>(bucketCount, bucketPtr, bucketCursor,
                                        rowPtr, B, N, E);
    fused3_k<<<eb + dqb, 256, 0, stream>>>(src, dst, bucketCursor, ebuf, E, B,
                                           h1, W2, b2, Wres, bres, Wattn, dinv,
                                           h, (float2*)hs, res, thv, N, eb, dqb);

    csr_build_k<<<B, 256, 0, stream>>>(ebuf, bucketPtr, rowPtr, dinv, srcSorted, N);

    spmm_k<<<spb, 256, 0, stream>>>((const float2*)hs, srcSorted, rowPtr, dinv,
                                    Wattn, (float4*)u1, u1s, tav, N);

    tail_k<<<tlb, 256, 0, stream>>>(u1s, srcSorted, rowPtr, dinv,
                                    h, u1, res, thv, tav, Wattn, battn,
                                    Wf1h, bf1, Wf2, bf2, W3h, b3, W4, b4,
                                    (float2*)d_out, N);
}